// Round 5
// baseline (736.698 us; speedup 1.0000x reference)
//
#include <hip/hip_runtime.h>
#include <hip/hip_bf16.h>

#define LTOT 4096
#define DM 256
#define BATCH 8
#define MROWS (BATCH * LTOT)     // 32768
#define NX ((size_t)MROWS * DM)  // 8388608 elements

typedef __bf16 bf16x8 __attribute__((ext_vector_type(8)));
typedef float f32x4 __attribute__((ext_vector_type(4)));

#define AS1 __attribute__((address_space(1)))
#define AS3 __attribute__((address_space(3)))

__device__ __forceinline__ float elu1(float x) {
    return x > 0.f ? x + 1.f : expf(x);
}
__device__ __forceinline__ ushort f2bf(float f) {
    unsigned u = __float_as_uint(f);
    u += 0x7FFFu + ((u >> 16) & 1u);
    return (ushort)(u >> 16);
}
__device__ __forceinline__ float b2f(ushort u) {
    return __uint_as_float(((unsigned)u) << 16);
}

// ---------------------------------------------------------------------------
// prep: XC[b,l,c] (row stride 512, left half) = bf16(feats[b,c,l] + pos(c,l))
// ---------------------------------------------------------------------------
__global__ __launch_bounds__(256) void prep_kernel(const float* __restrict__ feats,
                                                   ushort* __restrict__ XC) {
    __shared__ float tile[32][33];
    int b = blockIdx.z;
    int l0 = blockIdx.x * 32;
    int c0 = blockIdx.y * 32;
    int tx = threadIdx.x, ty = threadIdx.y;
#pragma unroll
    for (int j = 0; j < 4; ++j) {
        int c = c0 + ty + j * 8;
        tile[ty + j * 8][tx] = feats[((size_t)(b * DM + c)) * LTOT + l0 + tx];
    }
    __syncthreads();
#pragma unroll
    for (int j = 0; j < 4; ++j) {
        int l = l0 + ty + j * 8;
        int c = c0 + tx;
        int i2 = (c >> 2) * 2;
        float dv = expf((float)i2 * -0.07195578415156063f);
        int rem = c & 3;
        int y = l >> 6, xc = l & 63;
        float pos = (rem < 2) ? (float)(xc + 1) : (float)(y + 1);
        float arg = pos * dv;
        float pe = (rem & 1) ? cosf(arg) : sinf(arg);
        float val = tile[tx][ty + j * 8] + pe;
        size_t row = (size_t)(b * LTOT + l);
        XC[row * 512 + c] = f2bf(val);
    }
}

__global__ __launch_bounds__(256) void unprep_kernel(const float* __restrict__ X,
                                                     float* __restrict__ out) {
    __shared__ float tile[32][33];
    int b = blockIdx.z;
    int l0 = blockIdx.x * 32;
    int c0 = blockIdx.y * 32;
    int tx = threadIdx.x, ty = threadIdx.y;
#pragma unroll
    for (int j = 0; j < 4; ++j) {
        int l = l0 + ty + j * 8;
        tile[ty + j * 8][tx] = X[((size_t)(b * LTOT + l)) * DM + c0 + tx];
    }
    __syncthreads();
#pragma unroll
    for (int j = 0; j < 4; ++j) {
        int c = c0 + ty + j * 8;
        out[((size_t)(b * DM + c)) * LTOT + l0 + tx] = tile[tx][ty + j * 8];
    }
}

// ---------------------------------------------------------------------------
// ALL weight transposes in one dispatch.
// ---------------------------------------------------------------------------
__global__ __launch_bounds__(256) void wtrans_all(const float* __restrict__ Wq,
                                                  const float* __restrict__ Wk,
                                                  const float* __restrict__ Wv,
                                                  const float* __restrict__ Wm,
                                                  const float* __restrict__ W1,
                                                  const float* __restrict__ W2,
                                                  ushort* __restrict__ WTqkv,
                                                  ushort* __restrict__ WTm,
                                                  ushort* __restrict__ WT1,
                                                  ushort* __restrict__ WT2) {
    __shared__ float t[32][33];
    int idx = blockIdx.x;
    const float* W;
    ushort* WT;
    int K, N, KT, z, r;
    size_t in_ls, out_ls;
    if (idx < 1024) {
        int which = idx >> 8, local = idx & 255;
        K = 256; N = 256; KT = 8; in_ls = 65536;
        if (which == 0)      { W = Wq; WT = WTqkv;          out_ls = 196608; }
        else if (which == 1) { W = Wk; WT = WTqkv + 65536;  out_ls = 196608; }
        else if (which == 2) { W = Wv; WT = WTqkv + 131072; out_ls = 196608; }
        else                 { W = Wm; WT = WTm;            out_ls = 65536; }
        z = local >> 6; r = local & 63;
    } else if (idx < 2048) {
        int local = idx - 1024;
        K = 512; N = 512; KT = 16; in_ls = 262144; out_ls = 262144;
        W = W1; WT = WT1;
        z = local >> 8; r = local & 255;
    } else {
        int local = idx - 2048;
        K = 512; N = 256; KT = 16; in_ls = 131072; out_ls = 131072;
        W = W2; WT = WT2;
        z = local >> 7; r = local & 127;
    }
    int k0 = (r % KT) * 32, n0 = (r / KT) * 32;
    const float* Wz = W + (size_t)z * in_ls;
    ushort* WTz = WT + (size_t)z * out_ls;
    int tx = threadIdx.x & 31, ty = threadIdx.x >> 5;
#pragma unroll
    for (int j = 0; j < 4; ++j)
        t[ty + j * 8][tx] = Wz[(size_t)(k0 + ty + j * 8) * N + n0 + tx];
    __syncthreads();
#pragma unroll
    for (int j = 0; j < 4; ++j)
        WTz[(size_t)(n0 + ty + j * 8) * K + k0 + tx] = f2bf(t[tx][ty + j * 8]);
}

// ---------------------------------------------------------------------------
// Deep-accumulator 256x256 GEMM core (m201-class geometry, plain HIP).
// 512 threads = 8 waves (2M x 4N), wave tile 128x64, acc 8x4 frags (128 VGPR).
// BK=64 K-tiles; LDS = 2 bufs x (A[256][64] + B[256][64]) = 128 KB static.
// Schedule: ONE vmcnt-wait + ONE barrier per K-tile. Stage of tile kt+1 is
// issued at kt's entry (right after the buffer it overwrites is released),
// so the vmcnt(0) drain at kt+1's entry is covered by a FULL tile of compute
// (~2000 cy >> HBM latency). No barriers inside a tile: compiler interleaves
// ds_read/lgkmcnt/MFMA finely; setprio(1) wraps each 16-MFMA cluster (T5).
// Swizzle (both-sides, rule #21): LDS(row, slot) = G(row, (slot-row)&7);
// staged via pre-swizzled global source column (LDS dest linear, as
// global_load_lds requires), read at slot (gs+row)&7. Wave read covers all
// 32 banks uniformly -> conflict-free (R4-verified: counter went to 0).
// MODE: 0 = QKV (elu1 for col<512, else id), 1 = relu store,
//       2 = LN, no residual  -> XC[row*512+256+col] = bf16(LN(T))
//       3 = LN + residual    -> XC left += ; optional fp32 Xout
// ---------------------------------------------------------------------------
template <int MODE, int K>
__global__ __launch_bounds__(512, 2) void gemm8(const ushort* __restrict__ A, int lda,
                                                const ushort* __restrict__ Bt, int N,
                                                ushort* __restrict__ Cb,
                                                const float* __restrict__ g,
                                                const float* __restrict__ bta,
                                                float* __restrict__ Xout,
                                                ushort* __restrict__ XC) {
    constexpr int NT = K / 64;
    __shared__ ushort arena[65536];  // 128 KB: [buf][As 16384 | Bs 16384]
    int tid = threadIdx.x;
    int m0 = blockIdx.x * 256;
    int n0 = blockIdx.y * 256;
    int wave = tid >> 6, lane = tid & 63;
    int wm = (wave >> 2) * 128, wn = (wave & 3) * 64;
    int fm = lane & 15, kg = lane >> 4;

    // staging: instr i covers rows i*64 + wave*8 + (lane>>3), slot lane&7.
    // source col-slot pre-swizzled: cs = ((lane&7) - row)&7, row%8 = lane>>3.
    int w8 = wave * 8 + (lane >> 3);
    int cs = (((lane & 7) - (lane >> 3)) & 7) * 8;
    const ushort* Asrc = A + (size_t)(m0 + w8) * lda + cs;
    const ushort* Bsrc = Bt + (size_t)(n0 + w8) * K + cs;
    // read slots: k2-slice ks reads LDS slot (ks*4 + kg + row)&7; row%8 == fm%8
    const int ls0 = ((kg + fm) & 7) * 8;
    const int ls1 = ((4 + kg + fm) & 7) * 8;

    f32x4 acc[8][4] = {};

#define STAGE8(buf, kt)                                                               \
    do {                                                                              \
        _Pragma("unroll") for (int i = 0; i < 4; ++i) {                               \
            __builtin_amdgcn_global_load_lds(                                         \
                (const AS1 void*)(Asrc + (size_t)(i * 64) * lda + (kt) * 64),         \
                (AS3 void*)(arena + (buf) * 32768 + i * 4096 + wave * 512), 16, 0, 0);\
            __builtin_amdgcn_global_load_lds(                                         \
                (const AS1 void*)(Bsrc + (size_t)(i * 64) * K + (kt) * 64),           \
                (AS3 void*)(arena + (buf) * 32768 + 16384 + i * 4096 + wave * 512),   \
                16, 0, 0);                                                            \
        }                                                                             \
    } while (0)

    STAGE8(0, 0);
    if (NT > 1) STAGE8(1, 1);
#pragma unroll
    for (int kt = 0; kt < NT; ++kt) {
        if (kt == 0) asm volatile("s_waitcnt vmcnt(8)" ::: "memory");
        else         asm volatile("s_waitcnt vmcnt(0)" ::: "memory");
        __builtin_amdgcn_s_barrier();
        asm volatile("" ::: "memory");  // fence: no LDS access moves above barrier
        if (kt >= 1 && kt + 1 < NT) STAGE8((kt + 1) & 1, kt + 1);
        const ushort* Ab = arena + (kt & 1) * 32768 + (wm + fm) * 64;
        const ushort* Bb = arena + (kt & 1) * 32768 + 16384 + (wn + fm) * 64;
        bf16x8 bfr[4][2];
#pragma unroll
        for (int nj = 0; nj < 4; ++nj) {
            bfr[nj][0] = *(const bf16x8*)(Bb + nj * 1024 + ls0);
            bfr[nj][1] = *(const bf16x8*)(Bb + nj * 1024 + ls1);
        }
#pragma unroll
        for (int q = 0; q < 4; ++q) {
            bf16x8 a00 = *(const bf16x8*)(Ab + (2 * q) * 1024 + ls0);
            bf16x8 a01 = *(const bf16x8*)(Ab + (2 * q) * 1024 + ls1);
            bf16x8 a10 = *(const bf16x8*)(Ab + (2 * q + 1) * 1024 + ls0);
            bf16x8 a11 = *(const bf16x8*)(Ab + (2 * q + 1) * 1024 + ls1);
            __builtin_amdgcn_s_setprio(1);
#pragma unroll
            for (int nj = 0; nj < 4; ++nj) {
                acc[2 * q][nj] = __builtin_amdgcn_mfma_f32_16x16x32_bf16(a00, bfr[nj][0], acc[2 * q][nj], 0, 0, 0);
                acc[2 * q][nj] = __builtin_amdgcn_mfma_f32_16x16x32_bf16(a01, bfr[nj][1], acc[2 * q][nj], 0, 0, 0);
                acc[2 * q + 1][nj] = __builtin_amdgcn_mfma_f32_16x16x32_bf16(a10, bfr[nj][0], acc[2 * q + 1][nj], 0, 0, 0);
                acc[2 * q + 1][nj] = __builtin_amdgcn_mfma_f32_16x16x32_bf16(a11, bfr[nj][1], acc[2 * q + 1][nj], 0, 0, 0);
            }
            __builtin_amdgcn_s_setprio(0);
        }
    }
#undef STAGE8

    if (MODE <= 1) {
#pragma unroll
        for (int mi = 0; mi < 8; ++mi) {
            int grow0 = m0 + wm + mi * 16 + kg * 4;
#pragma unroll
            for (int r = 0; r < 4; ++r) {
                size_t rowoff = (size_t)(grow0 + r) * N;
#pragma unroll
                for (int nj = 0; nj < 4; ++nj) {
                    float v = acc[mi][nj][r];
                    int col = n0 + wn + nj * 16 + fm;
                    if (MODE == 1) v = fmaxf(v, 0.f);
                    if (MODE == 0) v = (col < 512) ? elu1(v) : v;
                    Cb[rowoff + col] = f2bf(v);
                }
            }
        }
    } else {
        // LN epilogue; scratch aliases arena (all DMA drained at last-tile entry)
        float* red = (float*)arena;            // 256*8 fp32 = 8 KB
        float* musig = ((float*)arena) + 2048; // 256*2 fp32
#pragma unroll
        for (int mi = 0; mi < 8; ++mi) {
#pragma unroll
            for (int r = 0; r < 4; ++r) {
                float s = acc[mi][0][r] + acc[mi][1][r] + acc[mi][2][r] + acc[mi][3][r];
                float q = acc[mi][0][r] * acc[mi][0][r] + acc[mi][1][r] * acc[mi][1][r] +
                          acc[mi][2][r] * acc[mi][2][r] + acc[mi][3][r] * acc[mi][3][r];
#pragma unroll
                for (int o = 1; o < 16; o <<= 1) {
                    s += __shfl_xor(s, o, 64);
                    q += __shfl_xor(q, o, 64);
                }
                if ((lane & 15) == 0) {
                    int rl = wm + mi * 16 + kg * 4 + r;  // 0..255
                    red[rl * 8 + (wave & 3)] = s;
                    red[rl * 8 + 4 + (wave & 3)] = q;
                }
            }
        }
        __syncthreads();
        if (tid < 256) {
            float s = red[tid * 8 + 0] + red[tid * 8 + 1] + red[tid * 8 + 2] + red[tid * 8 + 3];
            float q = red[tid * 8 + 4] + red[tid * 8 + 5] + red[tid * 8 + 6] + red[tid * 8 + 7];
            float mu = s * (1.f / 256.f);
            float var = q * (1.f / 256.f) - mu * mu;
            musig[tid * 2] = mu;
            musig[tid * 2 + 1] = rsqrtf(var + 1e-5f);
        }
        __syncthreads();
        float gv[4], bv[4];
#pragma unroll
        for (int nj = 0; nj < 4; ++nj) {
            int col = wn + nj * 16 + fm;
            gv[nj] = g[col];
            bv[nj] = bta[col];
        }
#pragma unroll
        for (int mi = 0; mi < 8; ++mi) {
#pragma unroll
            for (int r = 0; r < 4; ++r) {
                int rl = wm + mi * 16 + kg * 4 + r;
                float mu = musig[rl * 2], rstd = musig[rl * 2 + 1];
                size_t grow = (size_t)(m0 + rl);
#pragma unroll
                for (int nj = 0; nj < 4; ++nj) {
                    int col = wn + nj * 16 + fm;
                    float v = (acc[mi][nj][r] - mu) * rstd * gv[nj] + bv[nj];
                    if (MODE == 3) {
                        float x = b2f(XC[grow * 512 + col]) + v;
                        XC[grow * 512 + col] = f2bf(x);
                        if (Xout) Xout[grow * 256 + col] = x;
                    } else {
                        XC[grow * 512 + 256 + col] = f2bf(v);
                    }
                }
            }
        }
    }
}

// ---------------------------------------------------------------------------
// KV partials, LDS-free register-blocked (proven).
// ---------------------------------------------------------------------------
__global__ __launch_bounds__(256) void kv_kernel(const ushort* __restrict__ Kf,
                                                 const ushort* __restrict__ Vf,
                                                 int str,
                                                 float* __restrict__ KVp,
                                                 float* __restrict__ KSp) {
    __shared__ float redv[3][8][8][16];  // 12 KB
    __shared__ float redk[3][8][4];
    int tid = threadIdx.x;
    int bh = blockIdx.x, sp = blockIdx.y;
    int b = bh >> 3, h = bh & 7;
    int sg = tid >> 6, d2 = (tid >> 3) & 7, v2 = tid & 7;
    size_t rbase = (size_t)(b * LTOT + sp * 512 + sg * 128) * str;
    const ushort* Kp = Kf + rbase + h * 32 + d2 * 4;
    const ushort* Vp = Vf + rbase + h * 32 + v2 * 4;
    float acc[4][4] = {};
    float ks[4] = {};
#pragma unroll 4
    for (int s = 0; s < 128; ++s) {
        ushort4 k4 = *(const ushort4*)(Kp + (size_t)s * str);
        ushort4 v4 = *(const ushort4*)(Vp + (size_t)s * str);
        float kk0 = b2f(k4.x), kk1 = b2f(k4.y), kk2 = b2f(k4.z), kk3 = b2f(k4.w);
        float vv0 = b2f(v4.x), vv1 = b2f(v4.y), vv2 = b2f(v4.z), vv3 = b2f(v4.w);
        acc[0][0] += kk0 * vv0; acc[0][1] += kk0 * vv1; acc[0][2] += kk0 * vv2; acc[0][3] += kk0 * vv3;
        acc[1][0] += kk1 * vv0; acc[1][1] += kk1 * vv1; acc[1][2] += kk1 * vv2; acc[1][3] += kk1 * vv3;
        acc[2][0] += kk2 * vv0; acc[2][1] += kk2 * vv1; acc[2][2] += kk2 * vv2; acc[2][3] += kk2 * vv3;
        acc[3][0] += kk3 * vv0; acc[3][1] += kk3 * vv1; acc[3][2] += kk3 * vv2; acc[3][3] += kk3 * vv3;
        ks[0] += kk0; ks[1] += kk1; ks[2] += kk2; ks[3] += kk3;
    }
    if (sg > 0) {
#pragma unroll
        for (int i = 0; i < 4; ++i)
#pragma unroll
            for (int j = 0; j < 4; ++j)
                redv[sg - 1][d2][v2][i * 4 + j] = acc[i][j];
        if (v2 == 0) {
#pragma unroll
            for (int i = 0; i < 4; ++i) redk[sg - 1][d2][i] = ks[i];
        }
    }
    __syncthreads();
    if (sg == 0) {
#pragma unroll
        for (int t = 0; t < 3; ++t)
#pragma unroll
            for (int i = 0; i < 4; ++i)
#pragma unroll
                for (int j = 0; j < 4; ++j)
                    acc[i][j] += redv[t][d2][v2][i * 4 + j];
        float* base = KVp + (size_t)(sp * 64 + bh) * 1024;
#pragma unroll
        for (int i = 0; i < 4; ++i) {
            float4 o = make_float4(acc[i][0], acc[i][1], acc[i][2], acc[i][3]);
            *(float4*)(base + (d2 * 4 + i) * 32 + v2 * 4) = o;
        }
        if (v2 == 0) {
#pragma unroll
            for (int t = 0; t < 3; ++t)
#pragma unroll
                for (int i = 0; i < 4; ++i) ks[i] += redk[t][d2][i];
#pragma unroll
            for (int i = 0; i < 4; ++i)
                KSp[(sp * 64 + bh) * 32 + d2 * 4 + i] = ks[i];
        }
    }
}

// ---------------------------------------------------------------------------
// reduce partials -> KVT bf16 [bh][v][d] (transposed, mfma-B layout) + KS fp32
// ---------------------------------------------------------------------------
__global__ __launch_bounds__(256) void kvreduce_kernel(const float* __restrict__ KVp,
                                                       const float* __restrict__ KSp,
                                                       ushort* __restrict__ KVT,
                                                       float* __restrict__ KS) {
    int bh = blockIdx.x;
    int t = threadIdx.x;
    float4 s = make_float4(0.f, 0.f, 0.f, 0.f);
#pragma unroll
    for (int sp = 0; sp < 8; ++sp) {
        float4 v = *(const float4*)(KVp + ((size_t)(sp * 64 + bh)) * 1024 + t * 4);
        s.x += v.x; s.y += v.y; s.z += v.z; s.w += v.w;
    }
    int d = t >> 3, v0 = (t & 7) * 4;
    ushort* dst = KVT + (size_t)bh * 1024 + d;
    dst[(v0 + 0) * 32] = f2bf(s.x);
    dst[(v0 + 1) * 32] = f2bf(s.y);
    dst[(v0 + 2) * 32] = f2bf(s.z);
    dst[(v0 + 3) * 32] = f2bf(s.w);
    if (t < 32) {
        float ks = 0.f;
#pragma unroll
        for (int sp = 0; sp < 8; ++sp) ks += KSp[(sp * 64 + bh) * 32 + t];
        KS[bh * 32 + t] = ks;
    }
}

// ---------------------------------------------------------------------------
// msg via MFMA: msg[l, h*32+v] = (Q[l,h]·KV[h])[v] / (Q[l,h]·KS[h] + eps)
// ---------------------------------------------------------------------------
__global__ __launch_bounds__(256) void msg_mfma(const ushort* __restrict__ Qb, int qstr,
                                                const ushort* __restrict__ KVT,
                                                const float* __restrict__ KS,
                                                ushort* __restrict__ Msgb) {
    __shared__ ushort kvs[8 * 1280];  // [h][v][40] ushorts, 20 KB
    int tid = threadIdx.x;
    int b = blockIdx.y;
    int lc = blockIdx.x;  // 64-row chunk
    {
        const ushort* src = KVT + (size_t)b * 8192;
#pragma unroll
        for (int it = 0; it < 4; ++it) {
            int base = it * 2048 + tid * 8;
            int h = base >> 10, rem = base & 1023;
            int v = rem >> 5, d = rem & 31;
            bf16x8 val = *(const bf16x8*)(src + base);
            *(bf16x8*)(kvs + h * 1280 + v * 40 + d) = val;
        }
    }
    __syncthreads();
    int wave = tid >> 6, lane = tid & 63;
    int fm = lane & 15, kg = lane >> 4;
    int row0 = b * LTOT + lc * 64 + wave * 16;

    for (int h = 0; h < 8; ++h) {
        bf16x8 afr = *(const bf16x8*)(Qb + (size_t)(row0 + fm) * qstr + h * 32 + kg * 8);
        bf16x8 bfr0 = *(const bf16x8*)(kvs + h * 1280 + fm * 40 + kg * 8);
        bf16x8 bfr1 = *(const bf16x8*)(kvs + h * 1280 + (16 + fm) * 40 + kg * 8);
        f32x4 acc0 = {}, acc1 = {};
        acc0 = __builtin_amdgcn_mfma_f32_16x16x32_bf16(afr, bfr0, acc0, 0, 0, 0);
        acc1 = __builtin_amdgcn_mfma_f32_16x16x32_bf16(afr, bfr1, acc1, 0, 0, 0);
        const float* ksp = KS + (b * 8 + h) * 32 + kg * 8;
        float4 ka = *(const float4*)ksp;
        float4 kb = *(const float4*)(ksp + 4);
        float den = (float)afr[0] * ka.x + (float)afr[1] * ka.y +
                    (float)afr[2] * ka.z + (float)afr[3] * ka.w +
                    (float)afr[4] * kb.x + (float)afr[5] * kb.y +
                    (float)afr[6] * kb.z + (float)afr[7] * kb.w;
        den += __shfl_xor(den, 16, 64);
        den += __shfl_xor(den, 32, 64);
        float rz = 1.f / (den + 1e-6f);
#pragma unroll
        for (int r = 0; r < 4; ++r) {
            int rr = kg * 4 + r;
            float rzr = __shfl(rz, (kg << 4) | rr, 64);
            size_t ro = (size_t)(row0 + rr) * DM + h * 32;
            Msgb[ro + fm] = f2bf(acc0[r] * rzr);
            Msgb[ro + 16 + fm] = f2bf(acc1[r] * rzr);
        }
    }
}

// ---------------------------------------------------------------------------
// Orchestration
// ---------------------------------------------------------------------------
extern "C" void kernel_launch(void* const* d_in, const int* in_sizes, int n_in,
                              void* d_out, int out_size, void* d_ws, size_t ws_size,
                              hipStream_t stream) {
    const float* feats = (const float*)d_in[0];
    const float* Wq = (const float*)d_in[1];
    const float* Wk = (const float*)d_in[2];
    const float* Wv = (const float*)d_in[3];
    const float* Wm = (const float*)d_in[4];
    const float* W1 = (const float*)d_in[5];
    const float* W2 = (const float*)d_in[6];
    const float* g1 = (const float*)d_in[7];
    const float* b1 = (const float*)d_in[8];
    const float* g2 = (const float*)d_in[9];
    const float* b2 = (const float*)d_in[10];

    float* ws = (float*)d_ws;
    float* X = ws;                            // fp32 final x (written layer 3 only)
    ushort* XC = (ushort*)(ws + NX);          // bf16 [32768][512]: [x | LN1(msg)]
    ushort* QKVb = (ushort*)(ws + 2 * NX);    // bf16 [32768][768]; aliased by HBb
    ushort* HBb = QKVb;                       // bf16 [32768][512] MLP hidden

    // d_out doubles as scratch until the final unprep (32 MB)
    float* dout = (float*)d_out;
    ushort* msgb = (ushort*)dout;             // bf16 [32768][256] (16 MB)
    ushort* WB = (ushort*)dout + NX;
    ushort* WTqkv = WB;                       // [4][768][256]
    ushort* WTm = WB + 4 * 196608;            // [4][256][256]
    ushort* WT1 = WTm + 4 * 65536;            // [4][512][512]
    ushort* WT2 = WT1 + 4 * 262144;           // [4][256][512]
    float* KVp = dout + (NX + 2621440) / 2;   // [8][64][1024]
    float* KSp = KVp + 524288;                // [8][64][32]
    ushort* KVT = (ushort*)(KSp + 16384);     // [64][32][32] bf16 transposed
    float* KS = (float*)(KVT + 65536);        // [64][32]

    wtrans_all<<<2560, 256, 0, stream>>>(Wq, Wk, Wv, Wm, W1, W2, WTqkv, WTm, WT1, WT2);
    prep_kernel<<<dim3(128, 8, 8), dim3(32, 8), 0, stream>>>(feats, XC);

    for (int layer = 0; layer < 4; ++layer) {
        const ushort* wtqkv = WTqkv + (size_t)layer * 196608;
        const ushort* wtm = WTm + (size_t)layer * 65536;
        const ushort* wt1 = WT1 + (size_t)layer * 262144;
        const ushort* wt2 = WT2 + (size_t)layer * 131072;
        const float* lg1 = g1 + layer * DM;
        const float* lb1 = b1 + layer * DM;
        const float* lg2 = g2 + layer * DM;
        const float* lb2 = b2 + layer * DM;

        // QKV fused: [32768][768] = elu1/elu1/id( XC[:, :256] @ [Wq|Wk|Wv] )
        gemm8<0, 256><<<dim3(128, 3), 512, 0, stream>>>(XC, 512, wtqkv, 768, QKVb,
                                                        nullptr, nullptr, nullptr, nullptr);
        kv_kernel<<<dim3(64, 8), 256, 0, stream>>>(QKVb + 256, QKVb + 512, 768, KVp, KSp);
        kvreduce_kernel<<<64, 256, 0, stream>>>(KVp, KSp, KVT, KS);
        msg_mfma<<<dim3(64, 8), 256, 0, stream>>>(QKVb, 768, KVT, KS, msgb);
        // Wm GEMM + LN1 fused -> XC right half
        gemm8<2, 256><<<dim3(128, 1), 512, 0, stream>>>(msgb, 256, wtm, 256, nullptr,
                                                        lg1, lb1, nullptr, XC);
        // MLP1: relu( XC[:, :512] @ W1 ) -> HBb  (aliases QKVb, which is dead)
        gemm8<1, 512><<<dim3(128, 2), 512, 0, stream>>>(XC, 512, wt1, 512, HBb,
                                                        nullptr, nullptr, nullptr, nullptr);
        // MLP2 + LN2 + bf16 residual -> XC left; final layer also writes fp32 X
        gemm8<3, 512><<<dim3(128, 1), 512, 0, stream>>>(HBb, 512, wt2, 256, nullptr,
                                                        lg2, lb2, (layer == 3) ? X : nullptr, XC);
    }

    unprep_kernel<<<dim3(128, 8, 8), dim3(32, 8), 0, stream>>>(X, dout);
}

// Round 6
// 725.739 us; speedup vs baseline: 1.0151x; 1.0151x over previous
//
#include <hip/hip_runtime.h>
#include <hip/hip_bf16.h>

#define LTOT 4096
#define DM 256
#define BATCH 8
#define MROWS (BATCH * LTOT)     // 32768
#define NX ((size_t)MROWS * DM)  // 8388608 elements

typedef __bf16 bf16x8 __attribute__((ext_vector_type(8)));
typedef float f32x4 __attribute__((ext_vector_type(4)));

#define AS1 __attribute__((address_space(1)))
#define AS3 __attribute__((address_space(3)))

__device__ __forceinline__ float elu1(float x) {
    return x > 0.f ? x + 1.f : expf(x);
}
__device__ __forceinline__ ushort f2bf(float f) {
    unsigned u = __float_as_uint(f);
    u += 0x7FFFu + ((u >> 16) & 1u);
    return (ushort)(u >> 16);
}
__device__ __forceinline__ float b2f(ushort u) {
    return __uint_as_float(((unsigned)u) << 16);
}

// ---------------------------------------------------------------------------
// prep: XC[b,l,c] (row stride 512, left half) = bf16(feats[b,c,l] + pos(c,l))
// ---------------------------------------------------------------------------
__global__ __launch_bounds__(256) void prep_kernel(const float* __restrict__ feats,
                                                   ushort* __restrict__ XC) {
    __shared__ float tile[32][33];
    int b = blockIdx.z;
    int l0 = blockIdx.x * 32;
    int c0 = blockIdx.y * 32;
    int tx = threadIdx.x, ty = threadIdx.y;
#pragma unroll
    for (int j = 0; j < 4; ++j) {
        int c = c0 + ty + j * 8;
        tile[ty + j * 8][tx] = feats[((size_t)(b * DM + c)) * LTOT + l0 + tx];
    }
    __syncthreads();
#pragma unroll
    for (int j = 0; j < 4; ++j) {
        int l = l0 + ty + j * 8;
        int c = c0 + tx;
        int i2 = (c >> 2) * 2;
        float dv = expf((float)i2 * -0.07195578415156063f);
        int rem = c & 3;
        int y = l >> 6, xc = l & 63;
        float pos = (rem < 2) ? (float)(xc + 1) : (float)(y + 1);
        float arg = pos * dv;
        float pe = (rem & 1) ? cosf(arg) : sinf(arg);
        float val = tile[tx][ty + j * 8] + pe;
        size_t row = (size_t)(b * LTOT + l);
        XC[row * 512 + c] = f2bf(val);
    }
}

__global__ __launch_bounds__(256) void unprep_kernel(const float* __restrict__ X,
                                                     float* __restrict__ out) {
    __shared__ float tile[32][33];
    int b = blockIdx.z;
    int l0 = blockIdx.x * 32;
    int c0 = blockIdx.y * 32;
    int tx = threadIdx.x, ty = threadIdx.y;
#pragma unroll
    for (int j = 0; j < 4; ++j) {
        int l = l0 + ty + j * 8;
        tile[ty + j * 8][tx] = X[((size_t)(b * LTOT + l)) * DM + c0 + tx];
    }
    __syncthreads();
#pragma unroll
    for (int j = 0; j < 4; ++j) {
        int c = c0 + ty + j * 8;
        out[((size_t)(b * DM + c)) * LTOT + l0 + tx] = tile[tx][ty + j * 8];
    }
}

// ---------------------------------------------------------------------------
// ALL weight transposes in one dispatch.
// ---------------------------------------------------------------------------
__global__ __launch_bounds__(256) void wtrans_all(const float* __restrict__ Wq,
                                                  const float* __restrict__ Wk,
                                                  const float* __restrict__ Wv,
                                                  const float* __restrict__ Wm,
                                                  const float* __restrict__ W1,
                                                  const float* __restrict__ W2,
                                                  ushort* __restrict__ WTqkv,
                                                  ushort* __restrict__ WTm,
                                                  ushort* __restrict__ WT1,
                                                  ushort* __restrict__ WT2) {
    __shared__ float t[32][33];
    int idx = blockIdx.x;
    const float* W;
    ushort* WT;
    int K, N, KT, z, r;
    size_t in_ls, out_ls;
    if (idx < 1024) {
        int which = idx >> 8, local = idx & 255;
        K = 256; N = 256; KT = 8; in_ls = 65536;
        if (which == 0)      { W = Wq; WT = WTqkv;          out_ls = 196608; }
        else if (which == 1) { W = Wk; WT = WTqkv + 65536;  out_ls = 196608; }
        else if (which == 2) { W = Wv; WT = WTqkv + 131072; out_ls = 196608; }
        else                 { W = Wm; WT = WTm;            out_ls = 65536; }
        z = local >> 6; r = local & 63;
    } else if (idx < 2048) {
        int local = idx - 1024;
        K = 512; N = 512; KT = 16; in_ls = 262144; out_ls = 262144;
        W = W1; WT = WT1;
        z = local >> 8; r = local & 255;
    } else {
        int local = idx - 2048;
        K = 512; N = 256; KT = 16; in_ls = 131072; out_ls = 131072;
        W = W2; WT = WT2;
        z = local >> 7; r = local & 127;
    }
    int k0 = (r % KT) * 32, n0 = (r / KT) * 32;
    const float* Wz = W + (size_t)z * in_ls;
    ushort* WTz = WT + (size_t)z * out_ls;
    int tx = threadIdx.x & 31, ty = threadIdx.x >> 5;
#pragma unroll
    for (int j = 0; j < 4; ++j)
        t[ty + j * 8][tx] = Wz[(size_t)(k0 + ty + j * 8) * N + n0 + tx];
    __syncthreads();
#pragma unroll
    for (int j = 0; j < 4; ++j)
        WTz[(size_t)(n0 + ty + j * 8) * K + k0 + tx] = f2bf(t[tx][ty + j * 8]);
}

// ---------------------------------------------------------------------------
// bf16 MFMA GEMM, T4 counted-vmcnt pipeline + verified-zero-conflict swizzle,
// SINGLE barrier per K-step. 128x256 tile, 512 threads = 8 waves (2M x 4N).
// 3-deep LDS: with 3 bufs, stage(t+2) targets buf(t-1); any wave past the
// step-t wait-barrier has retired its step-(t-1) ds_reads (lgkm waits precede
// the consuming MFMAs) -> the trailing WAR barrier is redundant and removed.
// vmcnt(3) mid-loop (never 0), vmcnt(0) only at the final step.
// ACT: 2 relu, 3 elu+1 for col<512 else identity (QKV).
// ---------------------------------------------------------------------------
template <int ACT, int K>
__global__ __launch_bounds__(512, 2) void gemm_bf16(const ushort* __restrict__ A, int lda,
                                                    const ushort* __restrict__ Bt,
                                                    ushort* __restrict__ Cb,
                                                    int N) {
    constexpr int S = K / 32;
    __shared__ ushort As[3][4096];  // [buf][128][32]
    __shared__ ushort Bs[3][8192];  // [buf][256][32]
    int tid = threadIdx.x;
    int m0 = blockIdx.x * 128, n0 = blockIdx.y * 256;
    int wave = tid >> 6, lane = tid & 63;
    int wm = (wave >> 2) * 64, wn = (wave & 3) * 64;
    int fm = lane & 15, kg = lane >> 4;
    int rr = tid >> 2;
    int cc = (((tid & 3) - (tid >> 3)) & 3) * 8;        // pre-swizzled source slot
    int sa = ((kg + (fm >> 1)) & 3) * 8;                // swizzled read slot

    const ushort* Ag = A + (size_t)(m0 + rr) * lda + cc;
    const ushort* Bg = Bt + (size_t)(n0 + rr) * K + cc;
    const ushort* Bg2 = Bt + (size_t)(n0 + rr + 128) * K + cc;

    f32x4 acc[4][4] = {};

#define STAGE_G(buf, k0)                                                          \
    do {                                                                          \
        __builtin_amdgcn_global_load_lds((const AS1 void*)(Ag + (k0)),            \
                                         (AS3 void*)(&As[buf][wave * 512]),       \
                                         16, 0, 0);                               \
        __builtin_amdgcn_global_load_lds((const AS1 void*)(Bg + (k0)),            \
                                         (AS3 void*)(&Bs[buf][wave * 512]),       \
                                         16, 0, 0);                               \
        __builtin_amdgcn_global_load_lds((const AS1 void*)(Bg2 + (k0)),           \
                                         (AS3 void*)(&Bs[buf][4096 + wave * 512]),\
                                         16, 0, 0);                               \
    } while (0)

    STAGE_G(0, 0);
    STAGE_G(1, 32);
#pragma unroll
    for (int t = 0; t < S; ++t) {
        // drain oldest tile's 3 loads; keep the newer ones in flight
        if (t + 1 < S) asm volatile("s_waitcnt vmcnt(3)" ::: "memory");
        else           asm volatile("s_waitcnt vmcnt(0)" ::: "memory");
        __builtin_amdgcn_s_barrier();
        asm volatile("" ::: "memory");  // keep LDS reads/stage below the barrier
        const int rb = t % 3;
        bf16x8 afr[4], bfr[4];
#pragma unroll
        for (int i = 0; i < 4; ++i)
            afr[i] = *(const bf16x8*)(&As[rb][(wm + i * 16 + fm) * 32 + sa]);
#pragma unroll
        for (int j = 0; j < 4; ++j)
            bfr[j] = *(const bf16x8*)(&Bs[rb][(wn + j * 16 + fm) * 32 + sa]);
        if (t + 2 < S) STAGE_G((t + 2) % 3, (t + 2) * 32);
#pragma unroll
        for (int i = 0; i < 4; ++i)
#pragma unroll
            for (int j = 0; j < 4; ++j)
                acc[i][j] = __builtin_amdgcn_mfma_f32_16x16x32_bf16(afr[i], bfr[j], acc[i][j], 0, 0, 0);
        // no trailing barrier (WAR-safe via 3-buffer rotation; see header)
    }
#undef STAGE_G

#pragma unroll
    for (int i = 0; i < 4; ++i) {
        int grow0 = m0 + wm + i * 16 + kg * 4;
#pragma unroll
        for (int r = 0; r < 4; ++r) {
            size_t rowoff = (size_t)(grow0 + r) * N;
#pragma unroll
            for (int j = 0; j < 4; ++j) {
                float v = acc[i][j][r];
                int col = n0 + wn + j * 16 + fm;
                if (ACT == 2) v = fmaxf(v, 0.f);
                if (ACT == 3) v = (col < 512) ? elu1(v) : v;
                Cb[rowoff + col] = f2bf(v);
            }
        }
    }
}

// ---------------------------------------------------------------------------
// Fused GEMM + LayerNorm, same single-barrier pipeline + swizzle.
// 128 rows x 256 cols, 512 threads = 8 waves (2M x 4N).
// RES=0 (LN1):  XC[row*512 + 256 + col] = bf16(LN(T))
// RES=1 (LN2):  x = bf16(XC left) + LN(T); XC left = bf16(x);
//               if (Xout) Xout[row][col] = x  (fp32, final layer only)
// ---------------------------------------------------------------------------
template <int RES, int K>
__global__ __launch_bounds__(512, 2) void gemm_ln(const ushort* __restrict__ A, int lda,
                                                  const ushort* __restrict__ Bt,
                                                  const float* __restrict__ g,
                                                  const float* __restrict__ bta,
                                                  float* __restrict__ Xout,
                                                  ushort* __restrict__ XC) {
    constexpr int S = K / 32;
    __shared__ ushort As[3][4096];   // [buf][128][32]
    __shared__ ushort Bs[3][8192];   // [buf][256][32]
    __shared__ float red[128 * 8];
    __shared__ float musig[128 * 2];
    int tid = threadIdx.x;
    int m0 = blockIdx.x * 128;
    int wave = tid >> 6, lane = tid & 63;
    int wm = (wave >> 2) * 64, wn = (wave & 3) * 64;
    int fm = lane & 15, kg = lane >> 4;
    int rr = tid >> 2;
    int cc = (((tid & 3) - (tid >> 3)) & 3) * 8;
    int sa = ((kg + (fm >> 1)) & 3) * 8;

    const ushort* Ag = A + (size_t)(m0 + rr) * lda + cc;
    const ushort* Bg = Bt + (size_t)rr * K + cc;
    const ushort* Bg2 = Bt + (size_t)(rr + 128) * K + cc;

    f32x4 acc[4][4] = {};

#define STAGE_L(buf, k0)                                                          \
    do {                                                                          \
        __builtin_amdgcn_global_load_lds((const AS1 void*)(Ag + (k0)),            \
                                         (AS3 void*)(&As[buf][wave * 512]),       \
                                         16, 0, 0);                               \
        __builtin_amdgcn_global_load_lds((const AS1 void*)(Bg + (k0)),            \
                                         (AS3 void*)(&Bs[buf][wave * 512]),       \
                                         16, 0, 0);                               \
        __builtin_amdgcn_global_load_lds((const AS1 void*)(Bg2 + (k0)),           \
                                         (AS3 void*)(&Bs[buf][4096 + wave * 512]),\
                                         16, 0, 0);                               \
    } while (0)

    STAGE_L(0, 0);
    STAGE_L(1, 32);
#pragma unroll
    for (int t = 0; t < S; ++t) {
        if (t + 1 < S) asm volatile("s_waitcnt vmcnt(3)" ::: "memory");
        else           asm volatile("s_waitcnt vmcnt(0)" ::: "memory");
        __builtin_amdgcn_s_barrier();
        asm volatile("" ::: "memory");
        const int rb = t % 3;
        bf16x8 afr[4], bfr[4];
#pragma unroll
        for (int i = 0; i < 4; ++i)
            afr[i] = *(const bf16x8*)(&As[rb][(i * 16 + fm + wm) * 32 + sa]);
#pragma unroll
        for (int j = 0; j < 4; ++j)
            bfr[j] = *(const bf16x8*)(&Bs[rb][(wn + j * 16 + fm) * 32 + sa]);
        if (t + 2 < S) STAGE_L((t + 2) % 3, (t + 2) * 32);
#pragma unroll
        for (int i = 0; i < 4; ++i)
#pragma unroll
            for (int j = 0; j < 4; ++j)
                acc[i][j] = __builtin_amdgcn_mfma_f32_16x16x32_bf16(afr[i], bfr[j], acc[i][j], 0, 0, 0);
        // no trailing barrier
    }
#undef STAGE_L

    // LN partial sums: each wave reduces its 64-col band per row
#pragma unroll
    for (int i = 0; i < 4; ++i) {
#pragma unroll
        for (int r = 0; r < 4; ++r) {
            float s = acc[i][0][r] + acc[i][1][r] + acc[i][2][r] + acc[i][3][r];
            float q = acc[i][0][r] * acc[i][0][r] + acc[i][1][r] * acc[i][1][r] +
                      acc[i][2][r] * acc[i][2][r] + acc[i][3][r] * acc[i][3][r];
#pragma unroll
            for (int o = 1; o < 16; o <<= 1) {
                s += __shfl_xor(s, o, 64);
                q += __shfl_xor(q, o, 64);
            }
            if ((lane & 15) == 0) {
                int row = wm + i * 16 + kg * 4 + r;  // 0..127
                red[row * 8 + (wave & 3)] = s;
                red[row * 8 + 4 + (wave & 3)] = q;
            }
        }
    }
    __syncthreads();
    if (tid < 128) {
        float s = red[tid * 8 + 0] + red[tid * 8 + 1] + red[tid * 8 + 2] + red[tid * 8 + 3];
        float q = red[tid * 8 + 4] + red[tid * 8 + 5] + red[tid * 8 + 6] + red[tid * 8 + 7];
        float mu = s * (1.f / 256.f);
        float var = q * (1.f / 256.f) - mu * mu;
        musig[tid * 2] = mu;
        musig[tid * 2 + 1] = rsqrtf(var + 1e-5f);
    }
    __syncthreads();

    float gv[4], bv[4];
#pragma unroll
    for (int j = 0; j < 4; ++j) {
        int col = wn + j * 16 + fm;
        gv[j] = g[col];
        bv[j] = bta[col];
    }
#pragma unroll
    for (int i = 0; i < 4; ++i) {
#pragma unroll
        for (int r = 0; r < 4; ++r) {
            int rl = wm + i * 16 + kg * 4 + r;
            float mu = musig[rl * 2], rstd = musig[rl * 2 + 1];
            size_t grow = (size_t)(m0 + rl);
#pragma unroll
            for (int j = 0; j < 4; ++j) {
                int col = wn + j * 16 + fm;
                float v = (acc[i][j][r] - mu) * rstd * gv[j] + bv[j];
                if (RES) {
                    float x = b2f(XC[grow * 512 + col]) + v;
                    XC[grow * 512 + col] = f2bf(x);
                    if (Xout) Xout[grow * 256 + col] = x;
                } else {
                    XC[grow * 512 + 256 + col] = f2bf(v);
                }
            }
        }
    }
}

// ---------------------------------------------------------------------------
// KV partials, LDS-free register-blocked (proven).
// ---------------------------------------------------------------------------
__global__ __launch_bounds__(256) void kv_kernel(const ushort* __restrict__ Kf,
                                                 const ushort* __restrict__ Vf,
                                                 int str,
                                                 float* __restrict__ KVp,
                                                 float* __restrict__ KSp) {
    __shared__ float redv[3][8][8][16];  // 12 KB
    __shared__ float redk[3][8][4];
    int tid = threadIdx.x;
    int bh = blockIdx.x, sp = blockIdx.y;
    int b = bh >> 3, h = bh & 7;
    int sg = tid >> 6, d2 = (tid >> 3) & 7, v2 = tid & 7;
    size_t rbase = (size_t)(b * LTOT + sp * 512 + sg * 128) * str;
    const ushort* Kp = Kf + rbase + h * 32 + d2 * 4;
    const ushort* Vp = Vf + rbase + h * 32 + v2 * 4;
    float acc[4][4] = {};
    float ks[4] = {};
#pragma unroll 4
    for (int s = 0; s < 128; ++s) {
        ushort4 k4 = *(const ushort4*)(Kp + (size_t)s * str);
        ushort4 v4 = *(const ushort4*)(Vp + (size_t)s * str);
        float kk0 = b2f(k4.x), kk1 = b2f(k4.y), kk2 = b2f(k4.z), kk3 = b2f(k4.w);
        float vv0 = b2f(v4.x), vv1 = b2f(v4.y), vv2 = b2f(v4.z), vv3 = b2f(v4.w);
        acc[0][0] += kk0 * vv0; acc[0][1] += kk0 * vv1; acc[0][2] += kk0 * vv2; acc[0][3] += kk0 * vv3;
        acc[1][0] += kk1 * vv0; acc[1][1] += kk1 * vv1; acc[1][2] += kk1 * vv2; acc[1][3] += kk1 * vv3;
        acc[2][0] += kk2 * vv0; acc[2][1] += kk2 * vv1; acc[2][2] += kk2 * vv2; acc[2][3] += kk2 * vv3;
        acc[3][0] += kk3 * vv0; acc[3][1] += kk3 * vv1; acc[3][2] += kk3 * vv2; acc[3][3] += kk3 * vv3;
        ks[0] += kk0; ks[1] += kk1; ks[2] += kk2; ks[3] += kk3;
    }
    if (sg > 0) {
#pragma unroll
        for (int i = 0; i < 4; ++i)
#pragma unroll
            for (int j = 0; j < 4; ++j)
                redv[sg - 1][d2][v2][i * 4 + j] = acc[i][j];
        if (v2 == 0) {
#pragma unroll
            for (int i = 0; i < 4; ++i) redk[sg - 1][d2][i] = ks[i];
        }
    }
    __syncthreads();
    if (sg == 0) {
#pragma unroll
        for (int t = 0; t < 3; ++t)
#pragma unroll
            for (int i = 0; i < 4; ++i)
#pragma unroll
                for (int j = 0; j < 4; ++j)
                    acc[i][j] += redv[t][d2][v2][i * 4 + j];
        float* base = KVp + (size_t)(sp * 64 + bh) * 1024;
#pragma unroll
        for (int i = 0; i < 4; ++i) {
            float4 o = make_float4(acc[i][0], acc[i][1], acc[i][2], acc[i][3]);
            *(float4*)(base + (d2 * 4 + i) * 32 + v2 * 4) = o;
        }
        if (v2 == 0) {
#pragma unroll
            for (int t = 0; t < 3; ++t)
#pragma unroll
                for (int i = 0; i < 4; ++i) ks[i] += redk[t][d2][i];
#pragma unroll
            for (int i = 0; i < 4; ++i)
                KSp[(sp * 64 + bh) * 32 + d2 * 4 + i] = ks[i];
        }
    }
}

// ---------------------------------------------------------------------------
// msg via MFMA, with kvreduce FUSED into the prologue:
// each block reduces its b's KVp/KSp partials (L2-hot, 256 KB) directly into
// the LDS kvs[h][v][40] layout + ksl[h][32], then proceeds as before.
// msg[l, h*32+v] = (Q[l,h]·KV[h])[v] / (Q[l,h]·KS[h] + eps)
// ---------------------------------------------------------------------------
__global__ __launch_bounds__(256) void msg_mfma(const ushort* __restrict__ Qb, int qstr,
                                                const float* __restrict__ KVp,
                                                const float* __restrict__ KSp,
                                                ushort* __restrict__ Msgb) {
    __shared__ ushort kvs[8 * 1280];  // [h][v][40] ushorts, 20 KB
    __shared__ float ksl[8 * 32];     // [h][32] fp32
    int tid = threadIdx.x;
    int b = blockIdx.y;
    int lc = blockIdx.x;  // 64-row chunk
    {
        // reduce KVp partials: per h (32 threads), 256 float4-quads each
        int h = tid >> 5, t5 = tid & 31;
        const float* src = KVp + (size_t)(b * 8 + h) * 1024;
#pragma unroll
        for (int it = 0; it < 8; ++it) {
            int q4 = t5 * 8 + it;  // q4 = d*8 + v0/4  (d = q4>>3, v0 = (q4&7)*4)
            float4 s = make_float4(0.f, 0.f, 0.f, 0.f);
#pragma unroll
            for (int sp = 0; sp < 8; ++sp) {
                float4 v = *(const float4*)(src + (size_t)sp * 65536 + q4 * 4);
                s.x += v.x; s.y += v.y; s.z += v.z; s.w += v.w;
            }
            int d = q4 >> 3, v0 = (q4 & 7) * 4;
            ushort* dst = kvs + h * 1280 + d;
            dst[(v0 + 0) * 40] = f2bf(s.x);
            dst[(v0 + 1) * 40] = f2bf(s.y);
            dst[(v0 + 2) * 40] = f2bf(s.z);
            dst[(v0 + 3) * 40] = f2bf(s.w);
        }
        // reduce KSp: 8 h x 32 d = 256 = block size
        float ks = 0.f;
#pragma unroll
        for (int sp = 0; sp < 8; ++sp) ks += KSp[(sp * 64 + b * 8 + h) * 32 + t5];
        ksl[tid] = ks;
    }
    __syncthreads();
    int wave = tid >> 6, lane = tid & 63;
    int fm = lane & 15, kg = lane >> 4;
    int row0 = b * LTOT + lc * 64 + wave * 16;

    for (int h = 0; h < 8; ++h) {
        bf16x8 afr = *(const bf16x8*)(Qb + (size_t)(row0 + fm) * qstr + h * 32 + kg * 8);
        bf16x8 bfr0 = *(const bf16x8*)(kvs + h * 1280 + fm * 40 + kg * 8);
        bf16x8 bfr1 = *(const bf16x8*)(kvs + h * 1280 + (16 + fm) * 40 + kg * 8);
        f32x4 acc0 = {}, acc1 = {};
        acc0 = __builtin_amdgcn_mfma_f32_16x16x32_bf16(afr, bfr0, acc0, 0, 0, 0);
        acc1 = __builtin_amdgcn_mfma_f32_16x16x32_bf16(afr, bfr1, acc1, 0, 0, 0);
        const float* ksp = ksl + h * 32 + kg * 8;
        float4 ka = *(const float4*)ksp;
        float4 kb = *(const float4*)(ksp + 4);
        float den = (float)afr[0] * ka.x + (float)afr[1] * ka.y +
                    (float)afr[2] * ka.z + (float)afr[3] * ka.w +
                    (float)afr[4] * kb.x + (float)afr[5] * kb.y +
                    (float)afr[6] * kb.z + (float)afr[7] * kb.w;
        den += __shfl_xor(den, 16, 64);
        den += __shfl_xor(den, 32, 64);
        float rz = 1.f / (den + 1e-6f);
#pragma unroll
        for (int r = 0; r < 4; ++r) {
            int rr = kg * 4 + r;
            float rzr = __shfl(rz, (kg << 4) | rr, 64);
            size_t ro = (size_t)(row0 + rr) * DM + h * 32;
            Msgb[ro + fm] = f2bf(acc0[r] * rzr);
            Msgb[ro + 16 + fm] = f2bf(acc1[r] * rzr);
        }
    }
}

// ---------------------------------------------------------------------------
// Orchestration
// ---------------------------------------------------------------------------
extern "C" void kernel_launch(void* const* d_in, const int* in_sizes, int n_in,
                              void* d_out, int out_size, void* d_ws, size_t ws_size,
                              hipStream_t stream) {
    const float* feats = (const float*)d_in[0];
    const float* Wq = (const float*)d_in[1];
    const float* Wk = (const float*)d_in[2];
    const float* Wv = (const float*)d_in[3];
    const float* Wm = (const float*)d_in[4];
    const float* W1 = (const float*)d_in[5];
    const float* W2 = (const float*)d_in[6];
    const float* g1 = (const float*)d_in[7];
    const float* b1 = (const float*)d_in[8];
    const float* g2 = (const float*)d_in[9];
    const float* b2 = (const float*)d_in[10];

    float* ws = (float*)d_ws;
    float* X = ws;                            // fp32 final x (written layer 3 only)
    ushort* XC = (ushort*)(ws + NX);          // bf16 [32768][512]: [x | LN1(msg)]
    ushort* QKVb = (ushort*)(ws + 2 * NX);    // bf16 [32768][768]; aliased by HBb
    ushort* HBb = QKVb;                       // bf16 [32768][512] MLP hidden

    // d_out doubles as scratch until the final unprep (32 MB)
    float* dout = (float*)d_out;
    ushort* msgb = (ushort*)dout;             // bf16 [32768][256] (16 MB)
    ushort* WB = (ushort*)dout + NX;
    ushort* WTqkv = WB;                       // [4][768][256]
    ushort* WTm = WB + 4 * 196608;            // [4][256][256]
    ushort* WT1 = WTm + 4 * 65536;            // [4][512][512]
    ushort* WT2 = WT1 + 4 * 262144;           // [4][256][512]
    float* KVp = dout + (NX + 2621440) / 2;   // [8][64][1024]
    float* KSp = KVp + 524288;                // [8][64][32]

    wtrans_all<<<2560, 256, 0, stream>>>(Wq, Wk, Wv, Wm, W1, W2, WTqkv, WTm, WT1, WT2);
    prep_kernel<<<dim3(128, 8, 8), dim3(32, 8), 0, stream>>>(feats, XC);

    for (int layer = 0; layer < 4; ++layer) {
        const ushort* wtqkv = WTqkv + (size_t)layer * 196608;
        const ushort* wtm = WTm + (size_t)layer * 65536;
        const ushort* wt1 = WT1 + (size_t)layer * 262144;
        const ushort* wt2 = WT2 + (size_t)layer * 131072;
        const float* lg1 = g1 + layer * DM;
        const float* lb1 = b1 + layer * DM;
        const float* lg2 = g2 + layer * DM;
        const float* lb2 = b2 + layer * DM;

        // QKV fused: [32768][768] = elu1/elu1/id( XC[:, :256] @ [Wq|Wk|Wv] )
        gemm_bf16<3, 256><<<dim3(256, 3), 512, 0, stream>>>(XC, 512, wtqkv, QKVb, 768);
        kv_kernel<<<dim3(64, 8), 256, 0, stream>>>(QKVb + 256, QKVb + 512, 768, KVp, KSp);
        msg_mfma<<<dim3(64, 8), 256, 0, stream>>>(QKVb, 768, KVp, KSp, msgb);
        // Wm GEMM + LN1 fused -> XC right half
        gemm_ln<0, 256><<<256, 512, 0, stream>>>(msgb, 256, wtm, lg1, lb1, nullptr, XC);
        // MLP1: relu( XC[:, :512] @ W1 ) -> HBb  (aliases QKVb, which is dead)
        gemm_bf16<2, 512><<<dim3(256, 2), 512, 0, stream>>>(XC, 512, wt1, HBb, 512);
        // MLP2 + LN2 + bf16 residual -> XC left; final layer also writes fp32 X
        gemm_ln<1, 512><<<256, 512, 0, stream>>>(HBb, 512, wt2, lg2, lb2,
                                                 (layer == 3) ? X : nullptr, XC);
    }

    unprep_kernel<<<dim3(128, 8, 8), dim3(32, 8), 0, stream>>>(X, dout);
}

// Round 8
// 634.816 us; speedup vs baseline: 1.1605x; 1.1432x over previous
//
#include <hip/hip_runtime.h>
#include <hip/hip_bf16.h>

#define LTOT 4096
#define DM 256
#define BATCH 8
#define MROWS (BATCH * LTOT)     // 32768
#define NX ((size_t)MROWS * DM)  // 8388608 elements

typedef __bf16 bf16x8 __attribute__((ext_vector_type(8)));
typedef float f32x4 __attribute__((ext_vector_type(4)));

#define AS1 __attribute__((address_space(1)))
#define AS3 __attribute__((address_space(3)))

__device__ __forceinline__ float elu1(float x) {
    return x > 0.f ? x + 1.f : expf(x);
}
__device__ __forceinline__ ushort f2bf(float f) {
    unsigned u = __float_as_uint(f);
    u += 0x7FFFu + ((u >> 16) & 1u);
    return (ushort)(u >> 16);
}
__device__ __forceinline__ float b2f(ushort u) {
    return __uint_as_float(((unsigned)u) << 16);
}

// ---------------------------------------------------------------------------
// prep: XC[b,l,c] (row stride 512, left half) = bf16(feats[b,c,l] + pos(c,l))
// ---------------------------------------------------------------------------
__global__ __launch_bounds__(256) void prep_kernel(const float* __restrict__ feats,
                                                   ushort* __restrict__ XC) {
    __shared__ float tile[32][33];
    int b = blockIdx.z;
    int l0 = blockIdx.x * 32;
    int c0 = blockIdx.y * 32;
    int tx = threadIdx.x, ty = threadIdx.y;
#pragma unroll
    for (int j = 0; j < 4; ++j) {
        int c = c0 + ty + j * 8;
        tile[ty + j * 8][tx] = feats[((size_t)(b * DM + c)) * LTOT + l0 + tx];
    }
    __syncthreads();
#pragma unroll
    for (int j = 0; j < 4; ++j) {
        int l = l0 + ty + j * 8;
        int c = c0 + tx;
        int i2 = (c >> 2) * 2;
        float dv = expf((float)i2 * -0.07195578415156063f);
        int rem = c & 3;
        int y = l >> 6, xc = l & 63;
        float pos = (rem < 2) ? (float)(xc + 1) : (float)(y + 1);
        float arg = pos * dv;
        float pe = (rem & 1) ? cosf(arg) : sinf(arg);
        float val = tile[tx][ty + j * 8] + pe;
        size_t row = (size_t)(b * LTOT + l);
        XC[row * 512 + c] = f2bf(val);
    }
}

__global__ __launch_bounds__(256) void unprep_kernel(const float* __restrict__ X,
                                                     float* __restrict__ out) {
    __shared__ float tile[32][33];
    int b = blockIdx.z;
    int l0 = blockIdx.x * 32;
    int c0 = blockIdx.y * 32;
    int tx = threadIdx.x, ty = threadIdx.y;
#pragma unroll
    for (int j = 0; j < 4; ++j) {
        int l = l0 + ty + j * 8;
        tile[ty + j * 8][tx] = X[((size_t)(b * LTOT + l)) * DM + c0 + tx];
    }
    __syncthreads();
#pragma unroll
    for (int j = 0; j < 4; ++j) {
        int c = c0 + ty + j * 8;
        out[((size_t)(b * DM + c)) * LTOT + l0 + tx] = tile[tx][ty + j * 8];
    }
}

// ---------------------------------------------------------------------------
// ALL weight transposes in one dispatch.
// ---------------------------------------------------------------------------
__global__ __launch_bounds__(256) void wtrans_all(const float* __restrict__ Wq,
                                                  const float* __restrict__ Wk,
                                                  const float* __restrict__ Wv,
                                                  const float* __restrict__ Wm,
                                                  const float* __restrict__ W1,
                                                  const float* __restrict__ W2,
                                                  ushort* __restrict__ WTqkv,
                                                  ushort* __restrict__ WTm,
                                                  ushort* __restrict__ WT1,
                                                  ushort* __restrict__ WT2) {
    __shared__ float t[32][33];
    int idx = blockIdx.x;
    const float* W;
    ushort* WT;
    int K, N, KT, z, r;
    size_t in_ls, out_ls;
    if (idx < 1024) {
        int which = idx >> 8, local = idx & 255;
        K = 256; N = 256; KT = 8; in_ls = 65536;
        if (which == 0)      { W = Wq; WT = WTqkv;          out_ls = 196608; }
        else if (which == 1) { W = Wk; WT = WTqkv + 65536;  out_ls = 196608; }
        else if (which == 2) { W = Wv; WT = WTqkv + 131072; out_ls = 196608; }
        else                 { W = Wm; WT = WTm;            out_ls = 65536; }
        z = local >> 6; r = local & 63;
    } else if (idx < 2048) {
        int local = idx - 1024;
        K = 512; N = 512; KT = 16; in_ls = 262144; out_ls = 262144;
        W = W1; WT = WT1;
        z = local >> 8; r = local & 255;
    } else {
        int local = idx - 2048;
        K = 512; N = 256; KT = 16; in_ls = 131072; out_ls = 131072;
        W = W2; WT = WT2;
        z = local >> 7; r = local & 127;
    }
    int k0 = (r % KT) * 32, n0 = (r / KT) * 32;
    const float* Wz = W + (size_t)z * in_ls;
    ushort* WTz = WT + (size_t)z * out_ls;
    int tx = threadIdx.x & 31, ty = threadIdx.x >> 5;
#pragma unroll
    for (int j = 0; j < 4; ++j)
        t[ty + j * 8][tx] = Wz[(size_t)(k0 + ty + j * 8) * N + n0 + tx];
    __syncthreads();
#pragma unroll
    for (int j = 0; j < 4; ++j)
        WTz[(size_t)(n0 + ty + j * 8) * K + k0 + tx] = f2bf(t[tx][ty + j * 8]);
}

// ---------------------------------------------------------------------------
// bf16 MFMA GEMM, T4 counted-vmcnt pipeline + zero-conflict swizzle,
// SINGLE barrier per K-step (R6-proven: QKV 53.5 -> <41 us).
// 128x256 tile, 512 threads = 8 waves (2M x 4N).
// 3-deep LDS: stage(t+2) targets buf(t-1); any wave past the step-t
// wait-barrier has retired its step-(t-1) ds_reads -> trailing WAR barrier
// is redundant. vmcnt(3) mid-loop (never 0), vmcnt(0) only at final step.
// ACT: 2 relu, 3 elu+1 for col<512 else identity (QKV).
// ---------------------------------------------------------------------------
template <int ACT, int K>
__global__ __launch_bounds__(512, 2) void gemm_bf16(const ushort* __restrict__ A, int lda,
                                                    const ushort* __restrict__ Bt,
                                                    ushort* __restrict__ Cb,
                                                    int N) {
    constexpr int S = K / 32;
    __shared__ ushort As[3][4096];  // [buf][128][32]
    __shared__ ushort Bs[3][8192];  // [buf][256][32]
    int tid = threadIdx.x;
    int m0 = blockIdx.x * 128, n0 = blockIdx.y * 256;
    int wave = tid >> 6, lane = tid & 63;
    int wm = (wave >> 2) * 64, wn = (wave & 3) * 64;
    int fm = lane & 15, kg = lane >> 4;
    int rr = tid >> 2;
    int cc = (((tid & 3) - (tid >> 3)) & 3) * 8;        // pre-swizzled source slot
    int sa = ((kg + (fm >> 1)) & 3) * 8;                // swizzled read slot

    const ushort* Ag = A + (size_t)(m0 + rr) * lda + cc;
    const ushort* Bg = Bt + (size_t)(n0 + rr) * K + cc;
    const ushort* Bg2 = Bt + (size_t)(n0 + rr + 128) * K + cc;

    f32x4 acc[4][4] = {};

#define STAGE_G(buf, k0)                                                          \
    do {                                                                          \
        __builtin_amdgcn_global_load_lds((const AS1 void*)(Ag + (k0)),            \
                                         (AS3 void*)(&As[buf][wave * 512]),       \
                                         16, 0, 0);                               \
        __builtin_amdgcn_global_load_lds((const AS1 void*)(Bg + (k0)),            \
                                         (AS3 void*)(&Bs[buf][wave * 512]),       \
                                         16, 0, 0);                               \
        __builtin_amdgcn_global_load_lds((const AS1 void*)(Bg2 + (k0)),           \
                                         (AS3 void*)(&Bs[buf][4096 + wave * 512]),\
                                         16, 0, 0);                               \
    } while (0)

    STAGE_G(0, 0);
    STAGE_G(1, 32);
#pragma unroll
    for (int t = 0; t < S; ++t) {
        if (t + 1 < S) asm volatile("s_waitcnt vmcnt(3)" ::: "memory");
        else           asm volatile("s_waitcnt vmcnt(0)" ::: "memory");
        __builtin_amdgcn_s_barrier();
        asm volatile("" ::: "memory");  // keep LDS reads/stage below the barrier
        const int rb = t % 3;
        bf16x8 afr[4], bfr[4];
#pragma unroll
        for (int i = 0; i < 4; ++i)
            afr[i] = *(const bf16x8*)(&As[rb][(wm + i * 16 + fm) * 32 + sa]);
#pragma unroll
        for (int j = 0; j < 4; ++j)
            bfr[j] = *(const bf16x8*)(&Bs[rb][(wn + j * 16 + fm) * 32 + sa]);
        if (t + 2 < S) STAGE_G((t + 2) % 3, (t + 2) * 32);
#pragma unroll
        for (int i = 0; i < 4; ++i)
#pragma unroll
            for (int j = 0; j < 4; ++j)
                acc[i][j] = __builtin_amdgcn_mfma_f32_16x16x32_bf16(afr[i], bfr[j], acc[i][j], 0, 0, 0);
        // no trailing barrier (WAR-safe via 3-buffer rotation)
    }
#undef STAGE_G

#pragma unroll
    for (int i = 0; i < 4; ++i) {
        int grow0 = m0 + wm + i * 16 + kg * 4;
#pragma unroll
        for (int r = 0; r < 4; ++r) {
            size_t rowoff = (size_t)(grow0 + r) * N;
#pragma unroll
            for (int j = 0; j < 4; ++j) {
                float v = acc[i][j][r];
                int col = n0 + wn + j * 16 + fm;
                if (ACT == 2) v = fmaxf(v, 0.f);
                if (ACT == 3) v = (col < 512) ? elu1(v) : v;
                Cb[rowoff + col] = f2bf(v);
            }
        }
    }
}

// ---------------------------------------------------------------------------
// Fused GEMM + LayerNorm, same single-barrier pipeline + swizzle.
// 128 rows x 256 cols, 512 threads = 8 waves (2M x 4N).
// RES=0 (LN1):  XC[row*512 + 256 + col] = bf16(LN(T))
// RES=1 (LN2):  x = bf16(XC left) + LN(T); XC left = bf16(x);
//               if (Xout) Xout[row][col] = x  (fp32, final layer only)
// ---------------------------------------------------------------------------
template <int RES, int K>
__global__ __launch_bounds__(512, 2) void gemm_ln(const ushort* __restrict__ A, int lda,
                                                  const ushort* __restrict__ Bt,
                                                  const float* __restrict__ g,
                                                  const float* __restrict__ bta,
                                                  float* __restrict__ Xout,
                                                  ushort* __restrict__ XC) {
    constexpr int S = K / 32;
    __shared__ ushort As[3][4096];   // [buf][128][32]
    __shared__ ushort Bs[3][8192];   // [buf][256][32]
    __shared__ float red[128 * 8];
    __shared__ float musig[128 * 2];
    int tid = threadIdx.x;
    int m0 = blockIdx.x * 128;
    int wave = tid >> 6, lane = tid & 63;
    int wm = (wave >> 2) * 64, wn = (wave & 3) * 64;
    int fm = lane & 15, kg = lane >> 4;
    int rr = tid >> 2;
    int cc = (((tid & 3) - (tid >> 3)) & 3) * 8;
    int sa = ((kg + (fm >> 1)) & 3) * 8;

    const ushort* Ag = A + (size_t)(m0 + rr) * lda + cc;
    const ushort* Bg = Bt + (size_t)rr * K + cc;
    const ushort* Bg2 = Bt + (size_t)(rr + 128) * K + cc;

    f32x4 acc[4][4] = {};

#define STAGE_L(buf, k0)                                                          \
    do {                                                                          \
        __builtin_amdgcn_global_load_lds((const AS1 void*)(Ag + (k0)),            \
                                         (AS3 void*)(&As[buf][wave * 512]),       \
                                         16, 0, 0);                               \
        __builtin_amdgcn_global_load_lds((const AS1 void*)(Bg + (k0)),            \
                                         (AS3 void*)(&Bs[buf][wave * 512]),       \
                                         16, 0, 0);                               \
        __builtin_amdgcn_global_load_lds((const AS1 void*)(Bg2 + (k0)),           \
                                         (AS3 void*)(&Bs[buf][4096 + wave * 512]),\
                                         16, 0, 0);                               \
    } while (0)

    STAGE_L(0, 0);
    STAGE_L(1, 32);
#pragma unroll
    for (int t = 0; t < S; ++t) {
        if (t + 1 < S) asm volatile("s_waitcnt vmcnt(3)" ::: "memory");
        else           asm volatile("s_waitcnt vmcnt(0)" ::: "memory");
        __builtin_amdgcn_s_barrier();
        asm volatile("" ::: "memory");
        const int rb = t % 3;
        bf16x8 afr[4], bfr[4];
#pragma unroll
        for (int i = 0; i < 4; ++i)
            afr[i] = *(const bf16x8*)(&As[rb][(i * 16 + fm + wm) * 32 + sa]);
#pragma unroll
        for (int j = 0; j < 4; ++j)
            bfr[j] = *(const bf16x8*)(&Bs[rb][(wn + j * 16 + fm) * 32 + sa]);
        if (t + 2 < S) STAGE_L((t + 2) % 3, (t + 2) * 32);
#pragma unroll
        for (int i = 0; i < 4; ++i)
#pragma unroll
            for (int j = 0; j < 4; ++j)
                acc[i][j] = __builtin_amdgcn_mfma_f32_16x16x32_bf16(afr[i], bfr[j], acc[i][j], 0, 0, 0);
        // no trailing barrier
    }
#undef STAGE_L

    // LN partial sums: each wave reduces its 64-col band per row
#pragma unroll
    for (int i = 0; i < 4; ++i) {
#pragma unroll
        for (int r = 0; r < 4; ++r) {
            float s = acc[i][0][r] + acc[i][1][r] + acc[i][2][r] + acc[i][3][r];
            float q = acc[i][0][r] * acc[i][0][r] + acc[i][1][r] * acc[i][1][r] +
                      acc[i][2][r] * acc[i][2][r] + acc[i][3][r] * acc[i][3][r];
#pragma unroll
            for (int o = 1; o < 16; o <<= 1) {
                s += __shfl_xor(s, o, 64);
                q += __shfl_xor(q, o, 64);
            }
            if ((lane & 15) == 0) {
                int row = wm + i * 16 + kg * 4 + r;  // 0..127
                red[row * 8 + (wave & 3)] = s;
                red[row * 8 + 4 + (wave & 3)] = q;
            }
        }
    }
    __syncthreads();
    if (tid < 128) {
        float s = red[tid * 8 + 0] + red[tid * 8 + 1] + red[tid * 8 + 2] + red[tid * 8 + 3];
        float q = red[tid * 8 + 4] + red[tid * 8 + 5] + red[tid * 8 + 6] + red[tid * 8 + 7];
        float mu = s * (1.f / 256.f);
        float var = q * (1.f / 256.f) - mu * mu;
        musig[tid * 2] = mu;
        musig[tid * 2 + 1] = rsqrtf(var + 1e-5f);
    }
    __syncthreads();

    float gv[4], bv[4];
#pragma unroll
    for (int j = 0; j < 4; ++j) {
        int col = wn + j * 16 + fm;
        gv[j] = g[col];
        bv[j] = bta[col];
    }
#pragma unroll
    for (int i = 0; i < 4; ++i) {
#pragma unroll
        for (int r = 0; r < 4; ++r) {
            int rl = wm + i * 16 + kg * 4 + r;
            float mu = musig[rl * 2], rstd = musig[rl * 2 + 1];
            size_t grow = (size_t)(m0 + rl);
#pragma unroll
            for (int j = 0; j < 4; ++j) {
                int col = wn + j * 16 + fm;
                float v = (acc[i][j][r] - mu) * rstd * gv[j] + bv[j];
                if (RES) {
                    float x = b2f(XC[grow * 512 + col]) + v;
                    XC[grow * 512 + col] = f2bf(x);
                    if (Xout) Xout[grow * 256 + col] = x;
                } else {
                    XC[grow * 512 + 256 + col] = f2bf(v);
                }
            }
        }
    }
}

// ---------------------------------------------------------------------------
// KV partials, LDS-free register-blocked (proven).
// ---------------------------------------------------------------------------
__global__ __launch_bounds__(256) void kv_kernel(const ushort* __restrict__ Kf,
                                                 const ushort* __restrict__ Vf,
                                                 int str,
                                                 float* __restrict__ KVp,
                                                 float* __restrict__ KSp) {
    __shared__ float redv[3][8][8][16];  // 12 KB
    __shared__ float redk[3][8][4];
    int tid = threadIdx.x;
    int bh = blockIdx.x, sp = blockIdx.y;
    int b = bh >> 3, h = bh & 7;
    int sg = tid >> 6, d2 = (tid >> 3) & 7, v2 = tid & 7;
    size_t rbase = (size_t)(b * LTOT + sp * 512 + sg * 128) * str;
    const ushort* Kp = Kf + rbase + h * 32 + d2 * 4;
    const ushort* Vp = Vf + rbase + h * 32 + v2 * 4;
    float acc[4][4] = {};
    float ks[4] = {};
#pragma unroll 4
    for (int s = 0; s < 128; ++s) {
        ushort4 k4 = *(const ushort4*)(Kp + (size_t)s * str);
        ushort4 v4 = *(const ushort4*)(Vp + (size_t)s * str);
        float kk0 = b2f(k4.x), kk1 = b2f(k4.y), kk2 = b2f(k4.z), kk3 = b2f(k4.w);
        float vv0 = b2f(v4.x), vv1 = b2f(v4.y), vv2 = b2f(v4.z), vv3 = b2f(v4.w);
        acc[0][0] += kk0 * vv0; acc[0][1] += kk0 * vv1; acc[0][2] += kk0 * vv2; acc[0][3] += kk0 * vv3;
        acc[1][0] += kk1 * vv0; acc[1][1] += kk1 * vv1; acc[1][2] += kk1 * vv2; acc[1][3] += kk1 * vv3;
        acc[2][0] += kk2 * vv0; acc[2][1] += kk2 * vv1; acc[2][2] += kk2 * vv2; acc[2][3] += kk2 * vv3;
        acc[3][0] += kk3 * vv0; acc[3][1] += kk3 * vv1; acc[3][2] += kk3 * vv2; acc[3][3] += kk3 * vv3;
        ks[0] += kk0; ks[1] += kk1; ks[2] += kk2; ks[3] += kk3;
    }
    if (sg > 0) {
#pragma unroll
        for (int i = 0; i < 4; ++i)
#pragma unroll
            for (int j = 0; j < 4; ++j)
                redv[sg - 1][d2][v2][i * 4 + j] = acc[i][j];
        if (v2 == 0) {
#pragma unroll
            for (int i = 0; i < 4; ++i) redk[sg - 1][d2][i] = ks[i];
        }
    }
    __syncthreads();
    if (sg == 0) {
#pragma unroll
        for (int t = 0; t < 3; ++t)
#pragma unroll
            for (int i = 0; i < 4; ++i)
#pragma unroll
                for (int j = 0; j < 4; ++j)
                    acc[i][j] += redv[t][d2][v2][i * 4 + j];
        float* base = KVp + (size_t)(sp * 64 + bh) * 1024;
#pragma unroll
        for (int i = 0; i < 4; ++i) {
            float4 o = make_float4(acc[i][0], acc[i][1], acc[i][2], acc[i][3]);
            *(float4*)(base + (d2 * 4 + i) * 32 + v2 * 4) = o;
        }
        if (v2 == 0) {
#pragma unroll
            for (int t = 0; t < 3; ++t)
#pragma unroll
                for (int i = 0; i < 4; ++i) ks[i] += redk[t][d2][i];
#pragma unroll
            for (int i = 0; i < 4; ++i)
                KSp[(sp * 64 + bh) * 32 + d2 * 4 + i] = ks[i];
        }
    }
}

// ---------------------------------------------------------------------------
// reduce partials -> KVT bf16 [bh][v][d] (transposed, mfma-B layout) + KS fp32
// ---------------------------------------------------------------------------
__global__ __launch_bounds__(256) void kvreduce_kernel(const float* __restrict__ KVp,
                                                       const float* __restrict__ KSp,
                                                       ushort* __restrict__ KVT,
                                                       float* __restrict__ KS) {
    int bh = blockIdx.x;
    int t = threadIdx.x;
    float4 s = make_float4(0.f, 0.f, 0.f, 0.f);
#pragma unroll
    for (int sp = 0; sp < 8; ++sp) {
        float4 v = *(const float4*)(KVp + ((size_t)(sp * 64 + bh)) * 1024 + t * 4);
        s.x += v.x; s.y += v.y; s.z += v.z; s.w += v.w;
    }
    int d = t >> 3, v0 = (t & 7) * 4;
    ushort* dst = KVT + (size_t)bh * 1024 + d;
    dst[(v0 + 0) * 32] = f2bf(s.x);
    dst[(v0 + 1) * 32] = f2bf(s.y);
    dst[(v0 + 2) * 32] = f2bf(s.z);
    dst[(v0 + 3) * 32] = f2bf(s.w);
    if (t < 32) {
        float ks = 0.f;
#pragma unroll
        for (int sp = 0; sp < 8; ++sp) ks += KSp[(sp * 64 + bh) * 32 + t];
        KS[bh * 32 + t] = ks;
    }
}

// ---------------------------------------------------------------------------
// msg via MFMA: msg[l, h*32+v] = (Q[l,h]·KV[h])[v] / (Q[l,h]·KS[h] + eps)
// ---------------------------------------------------------------------------
__global__ __launch_bounds__(256) void msg_mfma(const ushort* __restrict__ Qb, int qstr,
                                                const ushort* __restrict__ KVT,
                                                const float* __restrict__ KS,
                                                ushort* __restrict__ Msgb) {
    __shared__ ushort kvs[8 * 1280];  // [h][v][40] ushorts, 20 KB
    int tid = threadIdx.x;
    int b = blockIdx.y;
    int lc = blockIdx.x;  // 64-row chunk
    {
        const ushort* src = KVT + (size_t)b * 8192;
#pragma unroll
        for (int it = 0; it < 4; ++it) {
            int base = it * 2048 + tid * 8;
            int h = base >> 10, rem = base & 1023;
            int v = rem >> 5, d = rem & 31;
            bf16x8 val = *(const bf16x8*)(src + base);
            *(bf16x8*)(kvs + h * 1280 + v * 40 + d) = val;
        }
    }
    __syncthreads();
    int wave = tid >> 6, lane = tid & 63;
    int fm = lane & 15, kg = lane >> 4;
    int row0 = b * LTOT + lc * 64 + wave * 16;

    for (int h = 0; h < 8; ++h) {
        bf16x8 afr = *(const bf16x8*)(Qb + (size_t)(row0 + fm) * qstr + h * 32 + kg * 8);
        bf16x8 bfr0 = *(const bf16x8*)(kvs + h * 1280 + fm * 40 + kg * 8);
        bf16x8 bfr1 = *(const bf16x8*)(kvs + h * 1280 + (16 + fm) * 40 + kg * 8);
        f32x4 acc0 = {}, acc1 = {};
        acc0 = __builtin_amdgcn_mfma_f32_16x16x32_bf16(afr, bfr0, acc0, 0, 0, 0);
        acc1 = __builtin_amdgcn_mfma_f32_16x16x32_bf16(afr, bfr1, acc1, 0, 0, 0);
        const float* ksp = KS + (b * 8 + h) * 32 + kg * 8;
        float4 ka = *(const float4*)ksp;
        float4 kb = *(const float4*)(ksp + 4);
        float den = (float)afr[0] * ka.x + (float)afr[1] * ka.y +
                    (float)afr[2] * ka.z + (float)afr[3] * ka.w +
                    (float)afr[4] * kb.x + (float)afr[5] * kb.y +
                    (float)afr[6] * kb.z + (float)afr[7] * kb.w;
        den += __shfl_xor(den, 16, 64);
        den += __shfl_xor(den, 32, 64);
        float rz = 1.f / (den + 1e-6f);
#pragma unroll
        for (int r = 0; r < 4; ++r) {
            int rr = kg * 4 + r;
            float rzr = __shfl(rz, (kg << 4) | rr, 64);
            size_t ro = (size_t)(row0 + rr) * DM + h * 32;
            Msgb[ro + fm] = f2bf(acc0[r] * rzr);
            Msgb[ro + 16 + fm] = f2bf(acc1[r] * rzr);
        }
    }
}

// ---------------------------------------------------------------------------
// Orchestration
// ---------------------------------------------------------------------------
extern "C" void kernel_launch(void* const* d_in, const int* in_sizes, int n_in,
                              void* d_out, int out_size, void* d_ws, size_t ws_size,
                              hipStream_t stream) {
    const float* feats = (const float*)d_in[0];
    const float* Wq = (const float*)d_in[1];
    const float* Wk = (const float*)d_in[2];
    const float* Wv = (const float*)d_in[3];
    const float* Wm = (const float*)d_in[4];
    const float* W1 = (const float*)d_in[5];
    const float* W2 = (const float*)d_in[6];
    const float* g1 = (const float*)d_in[7];
    const float* b1 = (const float*)d_in[8];
    const float* g2 = (const float*)d_in[9];
    const float* b2 = (const float*)d_in[10];

    float* ws = (float*)d_ws;
    float* X = ws;                            // fp32 final x (written layer 3 only)
    ushort* XC = (ushort*)(ws + NX);          // bf16 [32768][512]: [x | LN1(msg)]
    ushort* QKVb = (ushort*)(ws + 2 * NX);    // bf16 [32768][768]; aliased by HBb
    ushort* HBb = QKVb;                       // bf16 [32768][512] MLP hidden

    // d_out doubles as scratch until the final unprep (32 MB)
    float* dout = (float*)d_out;
    ushort* msgb = (ushort*)dout;             // bf16 [32768][256] (16 MB)
    ushort* WB = (ushort*)dout + NX;
    ushort* WTqkv = WB;                       // [4][768][256]
    ushort* WTm = WB + 4 * 196608;            // [4][256][256]
    ushort* WT1 = WTm + 4 * 65536;            // [4][512][512]
    ushort* WT2 = WT1 + 4 * 262144;           // [4][256][512]
    float* KVp = dout + (NX + 2621440) / 2;   // [8][64][1024]
    float* KSp = KVp + 524288;                // [8][64][32]
    ushort* KVT = (ushort*)(KSp + 16384);     // [64][32][32] bf16 transposed
    float* KS = (float*)(KVT + 65536);        // [64][32]

    wtrans_all<<<2560, 256, 0, stream>>>(Wq, Wk, Wv, Wm, W1, W2, WTqkv, WTm, WT1, WT2);
    prep_kernel<<<dim3(128, 8, 8), dim3(32, 8), 0, stream>>>(feats, XC);

    for (int layer = 0; layer < 4; ++layer) {
        const ushort* wtqkv = WTqkv + (size_t)layer * 196608;
        const ushort* wtm = WTm + (size_t)layer * 65536;
        const ushort* wt1 = WT1 + (size_t)layer * 262144;
        const ushort* wt2 = WT2 + (size_t)layer * 131072;
        const float* lg1 = g1 + layer * DM;
        const float* lb1 = b1 + layer * DM;
        const float* lg2 = g2 + layer * DM;
        const float* lb2 = b2 + layer * DM;

        // QKV fused: [32768][768] = elu1/elu1/id( XC[:, :256] @ [Wq|Wk|Wv] )
        gemm_bf16<3, 256><<<dim3(256, 3), 512, 0, stream>>>(XC, 512, wtqkv, QKVb, 768);
        kv_kernel<<<dim3(64, 8), 256, 0, stream>>>(QKVb + 256, QKVb + 512, 768, KVp, KSp);
        kvreduce_kernel<<<64, 256, 0, stream>>>(KVp, KSp, KVT, KS);
        msg_mfma<<<dim3(64, 8), 256, 0, stream>>>(QKVb, 768, KVT, KS, msgb);
        // Wm GEMM + LN1 fused -> XC right half
        gemm_ln<0, 256><<<256, 512, 0, stream>>>(msgb, 256, wtm, lg1, lb1, nullptr, XC);
        // MLP1: relu( XC[:, :512] @ W1 ) -> HBb  (aliases QKVb, which is dead)
        gemm_bf16<2, 512><<<dim3(256, 2), 512, 0, stream>>>(XC, 512, wt1, HBb, 512);
        // MLP2 + LN2 + bf16 residual -> XC left; final layer also writes fp32 X
        gemm_ln<1, 512><<<256, 512, 0, stream>>>(HBb, 512, wt2, lg2, lb2,
                                                 (layer == 3) ? X : nullptr, XC);
    }

    unprep_kernel<<<dim3(128, 8, 8), dim3(32, 8), 0, stream>>>(X, dout);
}

// Round 9
// 622.144 us; speedup vs baseline: 1.1841x; 1.0204x over previous
//
#include <hip/hip_runtime.h>
#include <hip/hip_bf16.h>

#define LTOT 4096
#define DM 256
#define BATCH 8
#define MROWS (BATCH * LTOT)     // 32768
#define NX ((size_t)MROWS * DM)  // 8388608 elements

typedef __bf16 bf16x8 __attribute__((ext_vector_type(8)));
typedef float f32x4 __attribute__((ext_vector_type(4)));

#define AS1 __attribute__((address_space(1)))
#define AS3 __attribute__((address_space(3)))

__device__ __forceinline__ float elu1(float x) {
    return x > 0.f ? x + 1.f : expf(x);
}
__device__ __forceinline__ ushort f2bf(float f) {
    unsigned u = __float_as_uint(f);
    u += 0x7FFFu + ((u >> 16) & 1u);
    return (ushort)(u >> 16);
}
__device__ __forceinline__ float b2f(ushort u) {
    return __uint_as_float(((unsigned)u) << 16);
}

// ---------------------------------------------------------------------------
// prep: XC[b,l,c] (row stride 512, left half) = bf16(feats[b,c,l] + pos(c,l))
// ---------------------------------------------------------------------------
__global__ __launch_bounds__(256) void prep_kernel(const float* __restrict__ feats,
                                                   ushort* __restrict__ XC) {
    __shared__ float tile[32][33];
    int b = blockIdx.z;
    int l0 = blockIdx.x * 32;
    int c0 = blockIdx.y * 32;
    int tx = threadIdx.x, ty = threadIdx.y;
#pragma unroll
    for (int j = 0; j < 4; ++j) {
        int c = c0 + ty + j * 8;
        tile[ty + j * 8][tx] = feats[((size_t)(b * DM + c)) * LTOT + l0 + tx];
    }
    __syncthreads();
#pragma unroll
    for (int j = 0; j < 4; ++j) {
        int l = l0 + ty + j * 8;
        int c = c0 + tx;
        int i2 = (c >> 2) * 2;
        float dv = expf((float)i2 * -0.07195578415156063f);
        int rem = c & 3;
        int y = l >> 6, xc = l & 63;
        float pos = (rem < 2) ? (float)(xc + 1) : (float)(y + 1);
        float arg = pos * dv;
        float pe = (rem & 1) ? cosf(arg) : sinf(arg);
        float val = tile[tx][ty + j * 8] + pe;
        size_t row = (size_t)(b * LTOT + l);
        XC[row * 512 + c] = f2bf(val);
    }
}

__global__ __launch_bounds__(256) void unprep_kernel(const float* __restrict__ X,
                                                     float* __restrict__ out) {
    __shared__ float tile[32][33];
    int b = blockIdx.z;
    int l0 = blockIdx.x * 32;
    int c0 = blockIdx.y * 32;
    int tx = threadIdx.x, ty = threadIdx.y;
#pragma unroll
    for (int j = 0; j < 4; ++j) {
        int l = l0 + ty + j * 8;
        tile[ty + j * 8][tx] = X[((size_t)(b * LTOT + l)) * DM + c0 + tx];
    }
    __syncthreads();
#pragma unroll
    for (int j = 0; j < 4; ++j) {
        int c = c0 + ty + j * 8;
        out[((size_t)(b * DM + c)) * LTOT + l0 + tx] = tile[tx][ty + j * 8];
    }
}

// ---------------------------------------------------------------------------
// ALL weight transposes in one dispatch.
// ---------------------------------------------------------------------------
__global__ __launch_bounds__(256) void wtrans_all(const float* __restrict__ Wq,
                                                  const float* __restrict__ Wk,
                                                  const float* __restrict__ Wv,
                                                  const float* __restrict__ Wm,
                                                  const float* __restrict__ W1,
                                                  const float* __restrict__ W2,
                                                  ushort* __restrict__ WTqkv,
                                                  ushort* __restrict__ WTm,
                                                  ushort* __restrict__ WT1,
                                                  ushort* __restrict__ WT2) {
    __shared__ float t[32][33];
    int idx = blockIdx.x;
    const float* W;
    ushort* WT;
    int K, N, KT, z, r;
    size_t in_ls, out_ls;
    if (idx < 1024) {
        int which = idx >> 8, local = idx & 255;
        K = 256; N = 256; KT = 8; in_ls = 65536;
        if (which == 0)      { W = Wq; WT = WTqkv;          out_ls = 196608; }
        else if (which == 1) { W = Wk; WT = WTqkv + 65536;  out_ls = 196608; }
        else if (which == 2) { W = Wv; WT = WTqkv + 131072; out_ls = 196608; }
        else                 { W = Wm; WT = WTm;            out_ls = 65536; }
        z = local >> 6; r = local & 63;
    } else if (idx < 2048) {
        int local = idx - 1024;
        K = 512; N = 512; KT = 16; in_ls = 262144; out_ls = 262144;
        W = W1; WT = WT1;
        z = local >> 8; r = local & 255;
    } else {
        int local = idx - 2048;
        K = 512; N = 256; KT = 16; in_ls = 131072; out_ls = 131072;
        W = W2; WT = WT2;
        z = local >> 7; r = local & 127;
    }
    int k0 = (r % KT) * 32, n0 = (r / KT) * 32;
    const float* Wz = W + (size_t)z * in_ls;
    ushort* WTz = WT + (size_t)z * out_ls;
    int tx = threadIdx.x & 31, ty = threadIdx.x >> 5;
#pragma unroll
    for (int j = 0; j < 4; ++j)
        t[ty + j * 8][tx] = Wz[(size_t)(k0 + ty + j * 8) * N + n0 + tx];
    __syncthreads();
#pragma unroll
    for (int j = 0; j < 4; ++j)
        WTz[(size_t)(n0 + ty + j * 8) * K + k0 + tx] = f2bf(t[tx][ty + j * 8]);
}

// ---------------------------------------------------------------------------
// bf16 MFMA GEMM, T4 counted-vmcnt pipeline, SINGLE barrier per K-step,
// LINEAR addressing (R9 ablation: swizzle reverted — it cost +22us on the
// staging coalescer in R2-vs-R4 while its conflict fix was off-critical-path).
// 128x256 tile, 512 threads = 8 waves (2M x 4N).
// 3-deep LDS: stage(t+2) targets buf(t-1); any wave past the step-t
// wait-barrier has retired its step-(t-1) ds_reads -> trailing WAR barrier
// is redundant. vmcnt(3) mid-loop (never 0), vmcnt(0) only at final step.
// ACT: 2 relu, 3 elu+1 for col<512 else identity (QKV).
// ---------------------------------------------------------------------------
template <int ACT, int K>
__global__ __launch_bounds__(512, 2) void gemm_bf16(const ushort* __restrict__ A, int lda,
                                                    const ushort* __restrict__ Bt,
                                                    ushort* __restrict__ Cb,
                                                    int N) {
    constexpr int S = K / 32;
    __shared__ ushort As[3][4096];  // [buf][128][32]
    __shared__ ushort Bs[3][8192];  // [buf][256][32]
    int tid = threadIdx.x;
    int m0 = blockIdx.x * 128, n0 = blockIdx.y * 256;
    int wave = tid >> 6, lane = tid & 63;
    int wm = (wave >> 2) * 64, wn = (wave & 3) * 64;
    int fm = lane & 15, kg = lane >> 4;
    int rr = tid >> 2, cc = (tid & 3) * 8;

    const ushort* Ag = A + (size_t)(m0 + rr) * lda + cc;
    const ushort* Bg = Bt + (size_t)(n0 + rr) * K + cc;
    const ushort* Bg2 = Bt + (size_t)(n0 + rr + 128) * K + cc;

    f32x4 acc[4][4] = {};

#define STAGE_G(buf, k0)                                                          \
    do {                                                                          \
        __builtin_amdgcn_global_load_lds((const AS1 void*)(Ag + (k0)),            \
                                         (AS3 void*)(&As[buf][wave * 512]),       \
                                         16, 0, 0);                               \
        __builtin_amdgcn_global_load_lds((const AS1 void*)(Bg + (k0)),            \
                                         (AS3 void*)(&Bs[buf][wave * 512]),       \
                                         16, 0, 0);                               \
        __builtin_amdgcn_global_load_lds((const AS1 void*)(Bg2 + (k0)),           \
                                         (AS3 void*)(&Bs[buf][4096 + wave * 512]),\
                                         16, 0, 0);                               \
    } while (0)

    STAGE_G(0, 0);
    STAGE_G(1, 32);
#pragma unroll
    for (int t = 0; t < S; ++t) {
        if (t + 1 < S) asm volatile("s_waitcnt vmcnt(3)" ::: "memory");
        else           asm volatile("s_waitcnt vmcnt(0)" ::: "memory");
        __builtin_amdgcn_s_barrier();
        asm volatile("" ::: "memory");  // keep LDS reads/stage below the barrier
        const int rb = t % 3;
        bf16x8 afr[4], bfr[4];
#pragma unroll
        for (int i = 0; i < 4; ++i)
            afr[i] = *(const bf16x8*)(&As[rb][(wm + i * 16 + fm) * 32 + kg * 8]);
#pragma unroll
        for (int j = 0; j < 4; ++j)
            bfr[j] = *(const bf16x8*)(&Bs[rb][(wn + j * 16 + fm) * 32 + kg * 8]);
        if (t + 2 < S) STAGE_G((t + 2) % 3, (t + 2) * 32);
#pragma unroll
        for (int i = 0; i < 4; ++i)
#pragma unroll
            for (int j = 0; j < 4; ++j)
                acc[i][j] = __builtin_amdgcn_mfma_f32_16x16x32_bf16(afr[i], bfr[j], acc[i][j], 0, 0, 0);
        // no trailing barrier (WAR-safe via 3-buffer rotation)
    }
#undef STAGE_G

#pragma unroll
    for (int i = 0; i < 4; ++i) {
        int grow0 = m0 + wm + i * 16 + kg * 4;
#pragma unroll
        for (int r = 0; r < 4; ++r) {
            size_t rowoff = (size_t)(grow0 + r) * N;
#pragma unroll
            for (int j = 0; j < 4; ++j) {
                float v = acc[i][j][r];
                int col = n0 + wn + j * 16 + fm;
                if (ACT == 2) v = fmaxf(v, 0.f);
                if (ACT == 3) v = (col < 512) ? elu1(v) : v;
                Cb[rowoff + col] = f2bf(v);
            }
        }
    }
}

// ---------------------------------------------------------------------------
// Fused GEMM + LayerNorm, same single-barrier pipeline, linear addressing.
// 128 rows x 256 cols, 512 threads = 8 waves (2M x 4N).
// RES=0 (LN1):  XC[row*512 + 256 + col] = bf16(LN(T))
// RES=1 (LN2):  x = bf16(XC left) + LN(T); XC left = bf16(x);
//               if (Xout) Xout[row][col] = x  (fp32, final layer only)
// ---------------------------------------------------------------------------
template <int RES, int K>
__global__ __launch_bounds__(512, 2) void gemm_ln(const ushort* __restrict__ A, int lda,
                                                  const ushort* __restrict__ Bt,
                                                  const float* __restrict__ g,
                                                  const float* __restrict__ bta,
                                                  float* __restrict__ Xout,
                                                  ushort* __restrict__ XC) {
    constexpr int S = K / 32;
    __shared__ ushort As[3][4096];   // [buf][128][32]
    __shared__ ushort Bs[3][8192];   // [buf][256][32]
    __shared__ float red[128 * 8];
    __shared__ float musig[128 * 2];
    int tid = threadIdx.x;
    int m0 = blockIdx.x * 128;
    int wave = tid >> 6, lane = tid & 63;
    int wm = (wave >> 2) * 64, wn = (wave & 3) * 64;
    int fm = lane & 15, kg = lane >> 4;
    int rr = tid >> 2, cc = (tid & 3) * 8;

    const ushort* Ag = A + (size_t)(m0 + rr) * lda + cc;
    const ushort* Bg = Bt + (size_t)rr * K + cc;
    const ushort* Bg2 = Bt + (size_t)(rr + 128) * K + cc;

    f32x4 acc[4][4] = {};

#define STAGE_L(buf, k0)                                                          \
    do {                                                                          \
        __builtin_amdgcn_global_load_lds((const AS1 void*)(Ag + (k0)),            \
                                         (AS3 void*)(&As[buf][wave * 512]),       \
                                         16, 0, 0);                               \
        __builtin_amdgcn_global_load_lds((const AS1 void*)(Bg + (k0)),            \
                                         (AS3 void*)(&Bs[buf][wave * 512]),       \
                                         16, 0, 0);                               \
        __builtin_amdgcn_global_load_lds((const AS1 void*)(Bg2 + (k0)),           \
                                         (AS3 void*)(&Bs[buf][4096 + wave * 512]),\
                                         16, 0, 0);                               \
    } while (0)

    STAGE_L(0, 0);
    STAGE_L(1, 32);
#pragma unroll
    for (int t = 0; t < S; ++t) {
        if (t + 1 < S) asm volatile("s_waitcnt vmcnt(3)" ::: "memory");
        else           asm volatile("s_waitcnt vmcnt(0)" ::: "memory");
        __builtin_amdgcn_s_barrier();
        asm volatile("" ::: "memory");
        const int rb = t % 3;
        bf16x8 afr[4], bfr[4];
#pragma unroll
        for (int i = 0; i < 4; ++i)
            afr[i] = *(const bf16x8*)(&As[rb][(i * 16 + fm + wm) * 32 + kg * 8]);
#pragma unroll
        for (int j = 0; j < 4; ++j)
            bfr[j] = *(const bf16x8*)(&Bs[rb][(wn + j * 16 + fm) * 32 + kg * 8]);
        if (t + 2 < S) STAGE_L((t + 2) % 3, (t + 2) * 32);
#pragma unroll
        for (int i = 0; i < 4; ++i)
#pragma unroll
            for (int j = 0; j < 4; ++j)
                acc[i][j] = __builtin_amdgcn_mfma_f32_16x16x32_bf16(afr[i], bfr[j], acc[i][j], 0, 0, 0);
        // no trailing barrier
    }
#undef STAGE_L

    // LN partial sums: each wave reduces its 64-col band per row
#pragma unroll
    for (int i = 0; i < 4; ++i) {
#pragma unroll
        for (int r = 0; r < 4; ++r) {
            float s = acc[i][0][r] + acc[i][1][r] + acc[i][2][r] + acc[i][3][r];
            float q = acc[i][0][r] * acc[i][0][r] + acc[i][1][r] * acc[i][1][r] +
                      acc[i][2][r] * acc[i][2][r] + acc[i][3][r] * acc[i][3][r];
#pragma unroll
            for (int o = 1; o < 16; o <<= 1) {
                s += __shfl_xor(s, o, 64);
                q += __shfl_xor(q, o, 64);
            }
            if ((lane & 15) == 0) {
                int row = wm + i * 16 + kg * 4 + r;  // 0..127
                red[row * 8 + (wave & 3)] = s;
                red[row * 8 + 4 + (wave & 3)] = q;
            }
        }
    }
    __syncthreads();
    if (tid < 128) {
        float s = red[tid * 8 + 0] + red[tid * 8 + 1] + red[tid * 8 + 2] + red[tid * 8 + 3];
        float q = red[tid * 8 + 4] + red[tid * 8 + 5] + red[tid * 8 + 6] + red[tid * 8 + 7];
        float mu = s * (1.f / 256.f);
        float var = q * (1.f / 256.f) - mu * mu;
        musig[tid * 2] = mu;
        musig[tid * 2 + 1] = rsqrtf(var + 1e-5f);
    }
    __syncthreads();

    float gv[4], bv[4];
#pragma unroll
    for (int j = 0; j < 4; ++j) {
        int col = wn + j * 16 + fm;
        gv[j] = g[col];
        bv[j] = bta[col];
    }
#pragma unroll
    for (int i = 0; i < 4; ++i) {
#pragma unroll
        for (int r = 0; r < 4; ++r) {
            int rl = wm + i * 16 + kg * 4 + r;
            float mu = musig[rl * 2], rstd = musig[rl * 2 + 1];
            size_t grow = (size_t)(m0 + rl);
#pragma unroll
            for (int j = 0; j < 4; ++j) {
                int col = wn + j * 16 + fm;
                float v = (acc[i][j][r] - mu) * rstd * gv[j] + bv[j];
                if (RES) {
                    float x = b2f(XC[grow * 512 + col]) + v;
                    XC[grow * 512 + col] = f2bf(x);
                    if (Xout) Xout[grow * 256 + col] = x;
                } else {
                    XC[grow * 512 + 256 + col] = f2bf(v);
                }
            }
        }
    }
}

// ---------------------------------------------------------------------------
// KV partials, LDS-free register-blocked (proven).
// ---------------------------------------------------------------------------
__global__ __launch_bounds__(256) void kv_kernel(const ushort* __restrict__ Kf,
                                                 const ushort* __restrict__ Vf,
                                                 int str,
                                                 float* __restrict__ KVp,
                                                 float* __restrict__ KSp) {
    __shared__ float redv[3][8][8][16];  // 12 KB
    __shared__ float redk[3][8][4];
    int tid = threadIdx.x;
    int bh = blockIdx.x, sp = blockIdx.y;
    int b = bh >> 3, h = bh & 7;
    int sg = tid >> 6, d2 = (tid >> 3) & 7, v2 = tid & 7;
    size_t rbase = (size_t)(b * LTOT + sp * 512 + sg * 128) * str;
    const ushort* Kp = Kf + rbase + h * 32 + d2 * 4;
    const ushort* Vp = Vf + rbase + h * 32 + v2 * 4;
    float acc[4][4] = {};
    float ks[4] = {};
#pragma unroll 4
    for (int s = 0; s < 128; ++s) {
        ushort4 k4 = *(const ushort4*)(Kp + (size_t)s * str);
        ushort4 v4 = *(const ushort4*)(Vp + (size_t)s * str);
        float kk0 = b2f(k4.x), kk1 = b2f(k4.y), kk2 = b2f(k4.z), kk3 = b2f(k4.w);
        float vv0 = b2f(v4.x), vv1 = b2f(v4.y), vv2 = b2f(v4.z), vv3 = b2f(v4.w);
        acc[0][0] += kk0 * vv0; acc[0][1] += kk0 * vv1; acc[0][2] += kk0 * vv2; acc[0][3] += kk0 * vv3;
        acc[1][0] += kk1 * vv0; acc[1][1] += kk1 * vv1; acc[1][2] += kk1 * vv2; acc[1][3] += kk1 * vv3;
        acc[2][0] += kk2 * vv0; acc[2][1] += kk2 * vv1; acc[2][2] += kk2 * vv2; acc[2][3] += kk2 * vv3;
        acc[3][0] += kk3 * vv0; acc[3][1] += kk3 * vv1; acc[3][2] += kk3 * vv2; acc[3][3] += kk3 * vv3;
        ks[0] += kk0; ks[1] += kk1; ks[2] += kk2; ks[3] += kk3;
    }
    if (sg > 0) {
#pragma unroll
        for (int i = 0; i < 4; ++i)
#pragma unroll
            for (int j = 0; j < 4; ++j)
                redv[sg - 1][d2][v2][i * 4 + j] = acc[i][j];
        if (v2 == 0) {
#pragma unroll
            for (int i = 0; i < 4; ++i) redk[sg - 1][d2][i] = ks[i];
        }
    }
    __syncthreads();
    if (sg == 0) {
#pragma unroll
        for (int t = 0; t < 3; ++t)
#pragma unroll
            for (int i = 0; i < 4; ++i)
#pragma unroll
                for (int j = 0; j < 4; ++j)
                    acc[i][j] += redv[t][d2][v2][i * 4 + j];
        float* base = KVp + (size_t)(sp * 64 + bh) * 1024;
#pragma unroll
        for (int i = 0; i < 4; ++i) {
            float4 o = make_float4(acc[i][0], acc[i][1], acc[i][2], acc[i][3]);
            *(float4*)(base + (d2 * 4 + i) * 32 + v2 * 4) = o;
        }
        if (v2 == 0) {
#pragma unroll
            for (int t = 0; t < 3; ++t)
#pragma unroll
                for (int i = 0; i < 4; ++i) ks[i] += redk[t][d2][i];
#pragma unroll
            for (int i = 0; i < 4; ++i)
                KSp[(sp * 64 + bh) * 32 + d2 * 4 + i] = ks[i];
        }
    }
}

// ---------------------------------------------------------------------------
// reduce partials -> KVT bf16 [bh][v][d] (transposed, mfma-B layout) + KS fp32
// ---------------------------------------------------------------------------
__global__ __launch_bounds__(256) void kvreduce_kernel(const float* __restrict__ KVp,
                                                       const float* __restrict__ KSp,
                                                       ushort* __restrict__ KVT,
                                                       float* __restrict__ KS) {
    int bh = blockIdx.x;
    int t = threadIdx.x;
    float4 s = make_float4(0.f, 0.f, 0.f, 0.f);
#pragma unroll
    for (int sp = 0; sp < 8; ++sp) {
        float4 v = *(const float4*)(KVp + ((size_t)(sp * 64 + bh)) * 1024 + t * 4);
        s.x += v.x; s.y += v.y; s.z += v.z; s.w += v.w;
    }
    int d = t >> 3, v0 = (t & 7) * 4;
    ushort* dst = KVT + (size_t)bh * 1024 + d;
    dst[(v0 + 0) * 32] = f2bf(s.x);
    dst[(v0 + 1) * 32] = f2bf(s.y);
    dst[(v0 + 2) * 32] = f2bf(s.z);
    dst[(v0 + 3) * 32] = f2bf(s.w);
    if (t < 32) {
        float ks = 0.f;
#pragma unroll
        for (int sp = 0; sp < 8; ++sp) ks += KSp[(sp * 64 + bh) * 32 + t];
        KS[bh * 32 + t] = ks;
    }
}

// ---------------------------------------------------------------------------
// msg via MFMA: msg[l, h*32+v] = (Q[l,h]·KV[h])[v] / (Q[l,h]·KS[h] + eps)
// ---------------------------------------------------------------------------
__global__ __launch_bounds__(256) void msg_mfma(const ushort* __restrict__ Qb, int qstr,
                                                const ushort* __restrict__ KVT,
                                                const float* __restrict__ KS,
                                                ushort* __restrict__ Msgb) {
    __shared__ ushort kvs[8 * 1280];  // [h][v][40] ushorts, 20 KB
    int tid = threadIdx.x;
    int b = blockIdx.y;
    int lc = blockIdx.x;  // 64-row chunk
    {
        const ushort* src = KVT + (size_t)b * 8192;
#pragma unroll
        for (int it = 0; it < 4; ++it) {
            int base = it * 2048 + tid * 8;
            int h = base >> 10, rem = base & 1023;
            int v = rem >> 5, d = rem & 31;
            bf16x8 val = *(const bf16x8*)(src + base);
            *(bf16x8*)(kvs + h * 1280 + v * 40 + d) = val;
        }
    }
    __syncthreads();
    int wave = tid >> 6, lane = tid & 63;
    int fm = lane & 15, kg = lane >> 4;
    int row0 = b * LTOT + lc * 64 + wave * 16;

    for (int h = 0; h < 8; ++h) {
        bf16x8 afr = *(const bf16x8*)(Qb + (size_t)(row0 + fm) * qstr + h * 32 + kg * 8);
        bf16x8 bfr0 = *(const bf16x8*)(kvs + h * 1280 + fm * 40 + kg * 8);
        bf16x8 bfr1 = *(const bf16x8*)(kvs + h * 1280 + (16 + fm) * 40 + kg * 8);
        f32x4 acc0 = {}, acc1 = {};
        acc0 = __builtin_amdgcn_mfma_f32_16x16x32_bf16(afr, bfr0, acc0, 0, 0, 0);
        acc1 = __builtin_amdgcn_mfma_f32_16x16x32_bf16(afr, bfr1, acc1, 0, 0, 0);
        const float* ksp = KS + (b * 8 + h) * 32 + kg * 8;
        float4 ka = *(const float4*)ksp;
        float4 kb = *(const float4*)(ksp + 4);
        float den = (float)afr[0] * ka.x + (float)afr[1] * ka.y +
                    (float)afr[2] * ka.z + (float)afr[3] * ka.w +
                    (float)afr[4] * kb.x + (float)afr[5] * kb.y +
                    (float)afr[6] * kb.z + (float)afr[7] * kb.w;
        den += __shfl_xor(den, 16, 64);
        den += __shfl_xor(den, 32, 64);
        float rz = 1.f / (den + 1e-6f);
#pragma unroll
        for (int r = 0; r < 4; ++r) {
            int rr = kg * 4 + r;
            float rzr = __shfl(rz, (kg << 4) | rr, 64);
            size_t ro = (size_t)(row0 + rr) * DM + h * 32;
            Msgb[ro + fm] = f2bf(acc0[r] * rzr);
            Msgb[ro + 16 + fm] = f2bf(acc1[r] * rzr);
        }
    }
}

// ---------------------------------------------------------------------------
// Orchestration
// ---------------------------------------------------------------------------
extern "C" void kernel_launch(void* const* d_in, const int* in_sizes, int n_in,
                              void* d_out, int out_size, void* d_ws, size_t ws_size,
                              hipStream_t stream) {
    const float* feats = (const float*)d_in[0];
    const float* Wq = (const float*)d_in[1];
    const float* Wk = (const float*)d_in[2];
    const float* Wv = (const float*)d_in[3];
    const float* Wm = (const float*)d_in[4];
    const float* W1 = (const float*)d_in[5];
    const float* W2 = (const float*)d_in[6];
    const float* g1 = (const float*)d_in[7];
    const float* b1 = (const float*)d_in[8];
    const float* g2 = (const float*)d_in[9];
    const float* b2 = (const float*)d_in[10];

    float* ws = (float*)d_ws;
    float* X = ws;                            // fp32 final x (written layer 3 only)
    ushort* XC = (ushort*)(ws + NX);          // bf16 [32768][512]: [x | LN1(msg)]
    ushort* QKVb = (ushort*)(ws + 2 * NX);    // bf16 [32768][768]; aliased by HBb
    ushort* HBb = QKVb;                       // bf16 [32768][512] MLP hidden

    // d_out doubles as scratch until the final unprep (32 MB)
    float* dout = (float*)d_out;
    ushort* msgb = (ushort*)dout;             // bf16 [32768][256] (16 MB)
    ushort* WB = (ushort*)dout + NX;
    ushort* WTqkv = WB;                       // [4][768][256]
    ushort* WTm = WB + 4 * 196608;            // [4][256][256]
    ushort* WT1 = WTm + 4 * 65536;            // [4][512][512]
    ushort* WT2 = WT1 + 4 * 262144;           // [4][256][512]
    float* KVp = dout + (NX + 2621440) / 2;   // [8][64][1024]
    float* KSp = KVp + 524288;                // [8][64][32]
    ushort* KVT = (ushort*)(KSp + 16384);     // [64][32][32] bf16 transposed
    float* KS = (float*)(KVT + 65536);        // [64][32]

    wtrans_all<<<2560, 256, 0, stream>>>(Wq, Wk, Wv, Wm, W1, W2, WTqkv, WTm, WT1, WT2);
    prep_kernel<<<dim3(128, 8, 8), dim3(32, 8), 0, stream>>>(feats, XC);

    for (int layer = 0; layer < 4; ++layer) {
        const ushort* wtqkv = WTqkv + (size_t)layer * 196608;
        const ushort* wtm = WTm + (size_t)layer * 65536;
        const ushort* wt1 = WT1 + (size_t)layer * 262144;
        const ushort* wt2 = WT2 + (size_t)layer * 131072;
        const float* lg1 = g1 + layer * DM;
        const float* lb1 = b1 + layer * DM;
        const float* lg2 = g2 + layer * DM;
        const float* lb2 = b2 + layer * DM;

        // QKV fused: [32768][768] = elu1/elu1/id( XC[:, :256] @ [Wq|Wk|Wv] )
        gemm_bf16<3, 256><<<dim3(256, 3), 512, 0, stream>>>(XC, 512, wtqkv, QKVb, 768);
        kv_kernel<<<dim3(64, 8), 256, 0, stream>>>(QKVb + 256, QKVb + 512, 768, KVp, KSp);
        kvreduce_kernel<<<64, 256, 0, stream>>>(KVp, KSp, KVT, KS);
        msg_mfma<<<dim3(64, 8), 256, 0, stream>>>(QKVb, 768, KVT, KS, msgb);
        // Wm GEMM + LN1 fused -> XC right half
        gemm_ln<0, 256><<<256, 512, 0, stream>>>(msgb, 256, wtm, lg1, lb1, nullptr, XC);
        // MLP1: relu( XC[:, :512] @ W1 ) -> HBb  (aliases QKVb, which is dead)
        gemm_bf16<2, 512><<<dim3(256, 2), 512, 0, stream>>>(XC, 512, wt1, HBb, 512);
        // MLP2 + LN2 + bf16 residual -> XC left; final layer also writes fp32 X
        gemm_ln<1, 512><<<256, 512, 0, stream>>>(HBb, 512, wt2, lg2, lb2,
                                                 (layer == 3) ? X : nullptr, XC);
    }

    unprep_kernel<<<dim3(128, 8, 8), dim3(32, 8), 0, stream>>>(X, dout);
}